// Round 9
// baseline (485.314 us; speedup 1.0000x reference)
//
#include <hip/hip_runtime.h>
#include <stdint.h>

// ---------- problem constants ----------
// WORLD MODEL: external inputs and d_out are FLOAT32 (ref is jnp.float32).
// Internal activations/weights bf16 for MFMA. Threshold 0.125 covers bf16.
#define BT    4096   // B*T
#define EDIM  1024
#define TLEN  2048
#define NH    16
#define DHH   64
#define DFFN  4096

typedef short short8 __attribute__((ext_vector_type(8)));
typedef float f32x4  __attribute__((ext_vector_type(4)));

typedef const __attribute__((address_space(1))) unsigned int* gas_ptr;
typedef __attribute__((address_space(3))) unsigned int*       las_ptr;

__device__ __forceinline__ float bf2f(unsigned short u) {
    union { unsigned int i; float f; } c; c.i = ((unsigned int)u) << 16; return c.f;
}
__device__ __forceinline__ unsigned short f2bf(float f) {
    union { float f; unsigned int i; } c; c.f = f;
    unsigned int u = c.i;
    unsigned int r = u + 0x7fffu + ((u >> 16) & 1u);   // RNE
    return (unsigned short)(r >> 16);
}
__device__ __forceinline__ unsigned short f2bf_trunc(float f) {
    union { float f; unsigned int i; } c; c.f = f;    // truncate: P-only (cheap)
    return (unsigned short)(c.i >> 16);
}
__device__ __forceinline__ float fexp2(float x) {
#if __has_builtin(__builtin_amdgcn_exp2f)
    return __builtin_amdgcn_exp2f(x);
#else
    return __expf(x * 0.69314718056f);
#endif
}
// async global->LDS 16B: per-lane global src, wave-uniform LDS base + lane*16.
__device__ __forceinline__ void gload16(const unsigned short* g, unsigned short* l) {
    __builtin_amdgcn_global_load_lds((gas_ptr)g, (las_ptr)l, 16, 0, 0);
}

// ---------------- weight transpose: f32 [K][N] -> bf16 [N][K] ----------------
// grid: (Nout/64, Kdim/64), 256 threads, 64x64 f32 tile in LDS.
template<int QKV>
__global__ __launch_bounds__(256) void transpose_kernel(
    const float* src, unsigned short* dst, int Kdim, int srcStride)
{
    __shared__ float T[64][65];
    int t = threadIdx.x;
    int n0 = blockIdx.x * 64, k0 = blockIdx.y * 64;
    int r = t >> 4, c4 = (t & 15) * 4;
    #pragma unroll
    for (int i = 0; i < 4; i++) {
        int rr = r + i * 16;
        const float* p;
        if (QKV) p = src + ((size_t)(n0 >> 6)) * 65536 + (size_t)(k0 + rr) * 64 + c4;
        else     p = src + (size_t)(k0 + rr) * srcStride + n0 + c4;
        float4 v = *(const float4*)p;
        T[c4 + 0][rr] = v.x;
        T[c4 + 1][rr] = v.y;
        T[c4 + 2][rr] = v.z;
        T[c4 + 3][rr] = v.w;
    }
    __syncthreads();
    int rn = t >> 2, ck = (t & 3) * 16;
    short8 o0, o1;
    #pragma unroll
    for (int j = 0; j < 8; j++) o0[j] = (short)f2bf(T[rn][ck + j]);
    #pragma unroll
    for (int j = 0; j < 8; j++) o1[j] = (short)f2bf(T[rn][ck + 8 + j]);
    unsigned short* dp = dst + (size_t)(n0 + rn) * Kdim + k0 + ck;
    *(short8*)dp       = o0;
    *(short8*)(dp + 8) = o1;
}

// ---------------- combined Wq/Wk/Wv transpose (grid.z = 3) -------------------
__global__ __launch_bounds__(256) void transpose_qkv3_kernel(
    const float* __restrict__ Wq, const float* __restrict__ Wk,
    const float* __restrict__ Wv, unsigned short* __restrict__ dstbase)
{
    __shared__ float T[64][65];
    int z = blockIdx.z;
    const float* src = (z == 0) ? Wq : (z == 1) ? Wk : Wv;
    unsigned short* dst = dstbase + (size_t)z * 1048576;
    int t = threadIdx.x;
    int n0 = blockIdx.x * 64, k0 = blockIdx.y * 64;
    int r = t >> 4, c4 = (t & 15) * 4;
    #pragma unroll
    for (int i = 0; i < 4; i++) {
        int rr = r + i * 16;
        const float* p = src + ((size_t)(n0 >> 6)) * 65536 + (size_t)(k0 + rr) * 64 + c4;
        float4 v = *(const float4*)p;
        T[c4 + 0][rr] = v.x;
        T[c4 + 1][rr] = v.y;
        T[c4 + 2][rr] = v.z;
        T[c4 + 3][rr] = v.w;
    }
    __syncthreads();
    int rn = t >> 2, ck = (t & 3) * 16;
    short8 o0, o1;
    #pragma unroll
    for (int j = 0; j < 8; j++) o0[j] = (short)f2bf(T[rn][ck + j]);
    #pragma unroll
    for (int j = 0; j < 8; j++) o1[j] = (short)f2bf(T[rn][ck + 8 + j]);
    unsigned short* dp = dst + (size_t)(n0 + rn) * EDIM + k0 + ck;
    *(short8*)dp       = o0;
    *(short8*)(dp + 8) = o1;
}

// ------------- combined FFN-half transpose: W1 slice + W2 slice (z=2) --------
__global__ __launch_bounds__(256) void transpose_ffn_kernel(
    const float* __restrict__ W1h, const float* __restrict__ W2h,
    unsigned short* __restrict__ w1t, unsigned short* __restrict__ w2t)
{
    __shared__ float T[64][65];
    int z = blockIdx.z;
    const float* src;
    unsigned short* dst;
    int Kdim, sstride, n0, k0;
    if (z == 0) { src = W1h; dst = w1t; Kdim = 1024; sstride = 4096;
                  n0 = blockIdx.x * 64; k0 = blockIdx.y * 64; }
    else        { src = W2h; dst = w2t; Kdim = 2048; sstride = 1024;
                  n0 = blockIdx.y * 64; k0 = blockIdx.x * 64; }
    int t = threadIdx.x;
    int r = t >> 4, c4 = (t & 15) * 4;
    #pragma unroll
    for (int i = 0; i < 4; i++) {
        int rr = r + i * 16;
        const float* p = src + (size_t)(k0 + rr) * sstride + n0 + c4;
        float4 v = *(const float4*)p;
        T[c4 + 0][rr] = v.x;
        T[c4 + 1][rr] = v.y;
        T[c4 + 2][rr] = v.z;
        T[c4 + 3][rr] = v.w;
    }
    __syncthreads();
    int rn = t >> 2, ck = (t & 3) * 16;
    short8 o0, o1;
    #pragma unroll
    for (int j = 0; j < 8; j++) o0[j] = (short)f2bf(T[rn][ck + j]);
    #pragma unroll
    for (int j = 0; j < 8; j++) o1[j] = (short)f2bf(T[rn][ck + 8 + j]);
    unsigned short* dp = dst + (size_t)(n0 + rn) * Kdim + k0 + ck;
    *(short8*)dp       = o0;
    *(short8*)(dp + 8) = o1;
}

// ---------------- V transpose: bf16 [bh][2048][64] -> bf16 [bh][64][2048] ----
__global__ __launch_bounds__(256) void vtrans_kernel(
    const unsigned short* __restrict__ v, unsigned short* __restrict__ vt)
{
    __shared__ __align__(16) unsigned short T[64][72];
    int bh = blockIdx.x, st = blockIdx.y;
    int t = threadIdx.x;
    int r = t >> 2, c = (t & 3) * 16;
    const unsigned short* src = v + ((size_t)bh * TLEN + st * 64) * DHH;
    short8 a0 = *(const short8*)(src + r * DHH + c);
    short8 a1 = *(const short8*)(src + r * DHH + c + 8);
    *(short8*)&T[r][c]     = a0;
    *(short8*)&T[r][c + 8] = a1;
    __syncthreads();
    int d = t >> 2;
    short8 o0, o1;
    #pragma unroll
    for (int j = 0; j < 8; j++) o0[j] = (short)T[c + j][d];
    #pragma unroll
    for (int j = 0; j < 8; j++) o1[j] = (short)T[c + 8 + j][d];
    unsigned short* dst = vt + ((size_t)bh * DHH + d) * TLEN + st * 64 + c;
    *(short8*)dst       = o0;
    *(short8*)(dst + 8) = o1;
}

// ---------------- fused QKV bias: [bq|bk|bv] -> f32[3072] ----------------
__global__ __launch_bounds__(256) void bias_fuse_kernel(
    const float* __restrict__ bq, const float* __restrict__ bk,
    const float* __restrict__ bv, float* __restrict__ dst)
{
    int t = blockIdx.x * 256 + threadIdx.x;           // grid 12 -> 3072
    const float* src = (t < 1024) ? bq : (t < 2048) ? bk : bv;
    dst[t] = src[t & 1023];
}

// ---------------- fused LN (stats + apply in one pass) -----------------------
template<int F32IN>
__global__ __launch_bounds__(256) void ln_fused_kernel(
    const void* __restrict__ x, const float* __restrict__ g,
    const float* __restrict__ b, unsigned short* __restrict__ out)
{
    int row = blockIdx.x, tid = threadIdx.x;
    size_t off = (size_t)row * EDIM + tid * 4;
    float v0, v1, v2, v3;
    if (F32IN) {
        float4 a = *(const float4*)((const float*)x + off);
        v0 = a.x; v1 = a.y; v2 = a.z; v3 = a.w;
    } else {
        ushort4 raw = *(const ushort4*)((const unsigned short*)x + off);
        v0 = bf2f(raw.x); v1 = bf2f(raw.y); v2 = bf2f(raw.z); v3 = bf2f(raw.w);
    }
    float s  = v0 + v1 + v2 + v3;
    float ss = v0*v0 + v1*v1 + v2*v2 + v3*v3;
    #pragma unroll
    for (int o = 1; o < 64; o <<= 1) {
        s  += __shfl_xor(s,  o, 64);
        ss += __shfl_xor(ss, o, 64);
    }
    __shared__ float red[8];
    int wave = tid >> 6;
    if ((tid & 63) == 0) { red[wave*2] = s; red[wave*2+1] = ss; }
    __syncthreads();
    s  = red[0] + red[2] + red[4] + red[6];
    ss = red[1] + red[3] + red[5] + red[7];
    float m  = s * (1.0f / EDIM);
    float rs = rsqrtf(ss * (1.0f / EDIM) - m * m + 1e-5f);
    float4 gv = *(const float4*)(g + tid * 4);
    float4 bv = *(const float4*)(b + tid * 4);
    ushort4 o;
    o.x = f2bf((v0 - m) * rs * gv.x + bv.x);
    o.y = f2bf((v1 - m) * rs * gv.y + bv.y);
    o.z = f2bf((v2 - m) * rs * gv.z + bv.z);
    o.w = f2bf((v3 - m) * rs * gv.w + bv.w);
    *(ushort4*)(out + off) = o;
}

// ---------------- gemm_bt: C = A[M][K] x B[N][K]^T, both bf16 ----------------
// BM=128, BK=64, BN template (128 or 64). 4 waves in 2x2.
// global_load_lds (width 16) staging into LINEAR LDS tiles (m97 structure).
// DBUF=1: T3-minimum 2-phase double-buffer (catalog recipe, m230/m248):
//   stage(t+1) issued BEFORE compute(t); ONE __syncthreads per iter whose
//   implicit vmcnt(0)+lgkmcnt(0) drain orders both "stage landed" and
//   "all waves' reads done" before the buffer is reused.
// Occupancy audit: BN=64 dbuf 48KB -> 3 blocks/CU (>= grid cap 2, no loss);
// BN=128 dbuf 64KB -> 2 (= FF1 grid cap). QKV (768 blocks = 3/CU) keeps
// DBUF=0 to preserve its 3 blocks/CU.
#define V_QKV  0
#define V_WO   1
#define V_FF1  2
#define V_FF2A 3
#define V_FF2B 4

template<int VARIANT, int BN, int DBUF>
__global__ __launch_bounds__(256) void gemm_bt_kernel(
    const unsigned short* A,        // bf16 [M][K]
    const unsigned short* Bt,       // bf16 [N][K] (transposed weight)
    const float* bias,              // f32 (not read for FF2A)
    const void* resid,              // WO: f32 x ; FF2B: bf16 x1 ; else unused
    void* out,                      // FF2A/B: f32 d_out ; else bf16
    int N, int K)
{
    constexpr int NJ  = BN / 32;    // also = B-tile gload issues per thread
    constexpr int ASZ = 128 * 64;   // elems per A buffer
    constexpr int BSZ = BN * 64;    // elems per B buffer
    __shared__ __align__(16) unsigned short As[(DBUF ? 2 : 1) * ASZ];
    __shared__ __align__(16) unsigned short Bs[(DBUF ? 2 : 1) * BSZ];
    int tid  = threadIdx.x;
    int lane = tid & 63, wave = tid >> 6;
    int quad = lane >> 4, l16 = lane & 15;
    int wr = wave >> 1, wc = wave & 1;
    int m0 = blockIdx.y * 128, n0 = blockIdx.x * BN;

    f32x4 acc[4][NJ];
    #pragma unroll
    for (int i = 0; i < 4; i++)
        #pragma unroll
        for (int j = 0; j < NJ; j++) acc[i][j] = (f32x4){0.f, 0.f, 0.f, 0.f};

    // staging geometry: one wave-issue covers 1024B = 8 rows of 128B (64 elems)
    int lr = lane >> 3;            // row within 8-row stripe
    int lc = (lane & 7) * 8;       // col elems (16B units)

    auto stage = [&](int b, int k0) {
        #pragma unroll
        for (int i = 0; i < 4; i++) {
            int r = (i * 4 + wave) * 8 + lr;
            gload16(A + (size_t)(m0 + r) * K + k0 + lc,
                    &As[b * ASZ + (i * 4 + wave) * 512]);
        }
        #pragma unroll
        for (int i = 0; i < NJ; i++) {
            int r = (i * 4 + wave) * 8 + lr;
            gload16(Bt + (size_t)(n0 + r) * K + k0 + lc,
                    &Bs[b * BSZ + (i * 4 + wave) * 512]);
        }
    };
    auto compute = [&](int b) {
        int ao = b * ASZ, bo = b * BSZ;
        #pragma unroll
        for (int ks = 0; ks < 2; ks++) {
            short8 af[4], bf[NJ];
            #pragma unroll
            for (int i = 0; i < 4; i++)
                af[i] = *(const short8*)(&As[ao + (wr * 64 + i * 16 + l16) * 64 + ks * 32 + quad * 8]);
            #pragma unroll
            for (int j = 0; j < NJ; j++)
                bf[j] = *(const short8*)(&Bs[bo + (wc * (BN / 2) + j * 16 + l16) * 64 + ks * 32 + quad * 8]);
            #pragma unroll
            for (int i = 0; i < 4; i++)
                #pragma unroll
                for (int j = 0; j < NJ; j++)
                    acc[i][j] = __builtin_amdgcn_mfma_f32_16x16x32_bf16(af[i], bf[j], acc[i][j], 0, 0, 0);
        }
    };

    if (DBUF) {
        int nt = K >> 6;
        stage(0, 0);
        __syncthreads();               // prologue: tile 0 ready
        int cur = 0;
        for (int t = 0; t < nt - 1; t++) {
            stage(cur ^ 1, (t + 1) << 6);   // overlaps compute below
            compute(cur);
            __syncthreads();           // drains stage; all reads of cur done
            cur ^= 1;
        }
        compute(cur);                  // epilogue tile (no prefetch)
    } else {
        for (int k0 = 0; k0 < K; k0 += 64) {
            stage(0, k0);
            __syncthreads();           // vmcnt(0) drain: tile ready
            compute(0);
            __syncthreads();           // readers done before next overwrite
        }
    }

    // epilogue: row = m0+wr*64+i*16+quad*4+r ; col = n0+wc*(BN/2)+j*16+l16
    #pragma unroll
    for (int j = 0; j < NJ; j++) {
        int c = n0 + wc * (BN / 2) + j * 16 + l16;
        float bi = (VARIANT == V_FF2A) ? 0.0f : bias[c];
        #pragma unroll
        for (int i = 0; i < 4; i++) {
            #pragma unroll
            for (int r = 0; r < 4; r++) {
                int m = m0 + wr * 64 + i * 16 + quad * 4 + r;
                float val = acc[i][j][r] + bi;
                if (VARIANT == V_WO)
                    val += ((const float*)resid)[(size_t)m * N + c];
                if (VARIANT == V_FF2B)
                    val += bf2f(((const unsigned short*)resid)[(size_t)m * N + c])
                         + ((const float*)out)[(size_t)m * N + c];   // partial from FF2A
                if (VARIANT == V_FF1)
                    val = fmaxf(val, 0.0f);
                if (VARIANT == V_QKV) {
                    int b = m >> 11, t = m & 2047;
                    int mat = c >> 10, cc = c & 1023;
                    int h = cc >> 6, d = cc & 63;
                    ((unsigned short*)out)[(size_t)mat * 4194304 +
                        (((size_t)(b * NH + h)) * TLEN + t) * DHH + d] = f2bf(val);
                } else if (VARIANT == V_FF2A || VARIANT == V_FF2B) {
                    ((float*)out)[(size_t)m * N + c] = val;
                } else {
                    ((unsigned short*)out)[(size_t)m * N + c] = f2bf(val);
                }
            }
        }
    }
}

// ---------------- flash attention v4.1 (proven best: 77.5us, VGPR 104) -------
// R5/R7 lessons: QBLK=128 variants (per-wave doubling OR 8-wave blocks) both
// regressed. v4.1's 1024-block grid + small per-wave state is the optimum.
__global__ __launch_bounds__(256) void attn_kernel(
    const unsigned short* __restrict__ q,
    const unsigned short* __restrict__ k,
    const unsigned short* __restrict__ vt,   // [bh][64 d][2048 s]
    unsigned short* __restrict__ att)
{
    __shared__ __align__(16) unsigned short Ks[128 * 72];     // 18.0 KB
    __shared__ __align__(16) unsigned short Vs[64 * 136];     // 17.0 KB
    __shared__ __align__(16) unsigned short Ps[4][16 * 136];  // 17.0 KB
    int tid  = threadIdx.x;
    int lane = tid & 63, wave = tid >> 6;
    int quad = lane >> 4, l16 = lane & 15;

    int flat = blockIdx.x;               // 0..1023
    int xcd  = flat & 7, idx = flat >> 3;
    int bh   = xcd * 4 + (idx >> 5);     // 4 heads per XCD
    int qt   = 31 - (idx & 31);          // descending chunk-count order
    int q0   = qt * 64;
    int qw   = q0 + wave * 16;           // this wave's 16 q-rows

    const unsigned short* Qb = q  + ((size_t)bh * TLEN + qw) * DHH;
    const unsigned short* Kb = k  + (size_t)bh * TLEN * DHH;
    const unsigned short* Vb = vt + (size_t)bh * DHH * TLEN;

    short8 aq0 = *(const short8*)(Qb + l16 * DHH + quad * 8);
    short8 aq1 = *(const short8*)(Qb + l16 * DHH + 32 + quad * 8);

    f32x4 o[4];
    #pragma unroll
    for (int n = 0; n < 4; n++) o[n] = (f32x4){0.f, 0.f, 0.f, 0.f};
    f32x4 mrow = {-1e30f, -1e30f, -1e30f, -1e30f};
    f32x4 lrow = {0.f, 0.f, 0.f, 0.f};        // per-lane partial denominator
    unsigned short* Pw = Ps[wave];
    const float cs = 0.18033688011f;          // 0.125 * log2(e)

    int rowK = tid >> 1, colK = (tid & 1) * 32;
    int rowV = tid >> 2, colV = (tid & 3) * 32;

    int nch = (q0 >> 7) + 1;             // block-uniform (exact for all waves)

    // prefetch chunk 0 into registers
    short8 ka0, ka1, ka2, ka3, va0, va1, va2, va3;
    {
        const unsigned short* kp = Kb + (size_t)rowK * DHH + colK;
        ka0 = *(const short8*)kp;
        ka1 = *(const short8*)(kp + 8);
        ka2 = *(const short8*)(kp + 16);
        ka3 = *(const short8*)(kp + 24);
        const unsigned short* vp = Vb + (size_t)rowV * TLEN + colV;
        va0 = *(const short8*)vp;
        va1 = *(const short8*)(vp + 8);
        va2 = *(const short8*)(vp + 16);
        va3 = *(const short8*)(vp + 24);
    }

    for (int ch = 0; ch < nch; ch++) {
        int s0 = ch * 128;
        __syncthreads();                 // all waves done reading prior chunk
        *(short8*)(&Ks[rowK * 72 + colK])       = ka0;
        *(short8*)(&Ks[rowK * 72 + colK + 8])   = ka1;
        *(short8*)(&Ks[rowK * 72 + colK + 16])  = ka2;
        *(short8*)(&Ks[rowK * 72 + colK + 24])  = ka3;
        *(short8*)(&Vs[rowV * 136 + colV])      = va0;
        *(short8*)(&Vs[rowV * 136 + colV + 8])  = va1;
        *(short8*)(&Vs[rowV * 136 + colV + 16]) = va2;
        *(short8*)(&Vs[rowV * 136 + colV + 24]) = va3;
        __syncthreads();                 // staged

        if (ch + 1 < nch) {              // T14: next chunk's loads hide here
            int s1 = s0 + 128;
            const unsigned short* kp = Kb + (size_t)(s1 + rowK) * DHH + colK;
            ka0 = *(const short8*)kp;
            ka1 = *(const short8*)(kp + 8);
            ka2 = *(const short8*)(kp + 16);
            ka3 = *(const short8*)(kp + 24);
            const unsigned short* vp = Vb + (size_t)rowV * TLEN + s1 + colV;
            va0 = *(const short8*)vp;
            va1 = *(const short8*)(vp + 8);
            va2 = *(const short8*)(vp + 16);
            va3 = *(const short8*)(vp + 24);
        }

        // ---- QK^T: S[q 16][s 128] ----
        f32x4 S[8];
        #pragma unroll
        for (int n = 0; n < 8; n++) {
            short8 b0 = *(const short8*)(&Ks[(n * 16 + l16) * 72 + quad * 8]);
            short8 b1 = *(const short8*)(&Ks[(n * 16 + l16) * 72 + 32 + quad * 8]);
            f32x4 s = (f32x4){0.f, 0.f, 0.f, 0.f};
            s = __builtin_amdgcn_mfma_f32_16x16x32_bf16(aq0, b0, s, 0, 0, 0);
            s = __builtin_amdgcn_mfma_f32_16x16x32_bf16(aq1, b1, s, 0, 0, 0);
            S[n] = s;
        }
        bool needmask = (s0 + 127 > qw);  // wave-uniform; true on diag chunk(s)
        // ---- online softmax (exp2 domain) ----
        #pragma unroll
        for (int r = 0; r < 4; r++) {
            float xv[8];
            #pragma unroll
            for (int n = 0; n < 8; n++) {
                float xx = S[n][r] * cs;
                if (needmask && (s0 + n * 16 + l16 > qw + quad * 4 + r)) xx = -1e30f;
                xv[n] = xx;
            }
            float mxl = fmaxf(fmaxf(fmaxf(xv[0], xv[1]), fmaxf(xv[2], xv[3])),
                              fmaxf(fmaxf(xv[4], xv[5]), fmaxf(xv[6], xv[7])));
            float used;
            if (__all(mxl <= mrow[r] + 8.0f)) {       // defer-rescale (T13)
                used = mrow[r];
            } else {
                float mx = mxl;
                mx = fmaxf(mx, __shfl_xor(mx, 1, 64));
                mx = fmaxf(mx, __shfl_xor(mx, 2, 64));
                mx = fmaxf(mx, __shfl_xor(mx, 4, 64));
                mx = fmaxf(mx, __shfl_xor(mx, 8, 64));
                float mnew  = fmaxf(mrow[r], mx);
                float alpha = fexp2(mrow[r] - mnew);
                lrow[r] *= alpha;
                o[0][r] *= alpha; o[1][r] *= alpha;
                o[2][r] *= alpha; o[3][r] *= alpha;
                mrow[r] = mnew;
                used = mnew;
            }
            float ps = 0.f;
            int prow = (quad * 4 + r) * 136;
            #pragma unroll
            for (int n = 0; n < 8; n++) {
                float p = fexp2(xv[n] - used);
                ps += p;
                Pw[prow + n * 16 + l16] = f2bf_trunc(p);
            }
            lrow[r] += ps;
        }
        // ---- PV: O += P[16x128] * V[128x64] ----
        short8 ap[4];
        #pragma unroll
        for (int ks = 0; ks < 4; ks++)
            ap[ks] = *(const short8*)(Pw + l16 * 136 + ks * 32 + quad * 8);
        #pragma unroll
        for (int n = 0; n < 4; n++) {
            #pragma unroll
            for (int ks = 0; ks < 4; ks++) {
                short8 b = *(const short8*)(&Vs[(n * 16 + l16) * 136 + ks * 32 + quad * 8]);
                o[n] = __builtin_amdgcn_mfma_f32_16x16x32_bf16(ap[ks], b, o[n], 0, 0, 0);
            }
        }
    }

    int bidx = bh >> 4, hh = bh & 15;
    #pragma unroll
    for (int r = 0; r < 4; r++) {
        float ls = lrow[r];
        ls += __shfl_xor(ls, 1, 64);
        ls += __shfl_xor(ls, 2, 64);
        ls += __shfl_xor(ls, 4, 64);
        ls += __shfl_xor(ls, 8, 64);
        float inv = 1.0f / ls;
        int t = qw + quad * 4 + r;
        size_t rowoff = ((size_t)(bidx * TLEN + t)) * EDIM + hh * 64;
        #pragma unroll
        for (int n = 0; n < 4; n++)
            att[rowoff + n * 16 + l16] = f2bf(o[n][r] * inv);
    }
}

// ---------------- launcher ----------------
extern "C" void kernel_launch(void* const* d_in, const int* in_sizes, int n_in,
                              void* d_out, int out_size, void* d_ws, size_t ws_size,
                              hipStream_t stream)
{
    (void)in_sizes; (void)n_in; (void)out_size; (void)ws_size;
    const float* x   = (const float*)d_in[0];
    const float* Wq  = (const float*)d_in[1];
    const float* bq  = (const float*)d_in[2];
    const float* Wk  = (const float*)d_in[3];
    const float* bk  = (const float*)d_in[4];
    const float* Wv  = (const float*)d_in[5];
    const float* bv  = (const float*)d_in[6];
    const float* Wo  = (const float*)d_in[7];
    const float* bo  = (const float*)d_in[8];
    const float* W1  = (const float*)d_in[9];
    const float* b1  = (const float*)d_in[10];
    const float* W2  = (const float*)d_in[11];
    const float* b2  = (const float*)d_in[12];
    const float* g1  = (const float*)d_in[13];
    const float* be1 = (const float*)d_in[14];
    const float* g2  = (const float*)d_in[15];
    const float* be2 = (const float*)d_in[16];

    // ws layout (ushort elems; total byte use < proven 42,008,640):
    //   xn/vtg/xn2 bytes 0..8M | q 8..16M (later x1) | k 16..24M (later WoT/W1T
    //   16..20M, W2T 20..24M) | v 24..32M | WqT/WkT/WvT 32..38M (contiguous
    //   [3072][1024] for fused QKV) then att 32..40M | biasf @ elem 19922944
    //   (byte 39,845,888; live only during QKV, att overwrites later) |
    //   h 24..40M (over v+att)
    unsigned short* ws  = (unsigned short*)d_ws;
    unsigned short* xn  = ws;                  // 4096x1024 bf16 (xn, vtg, xn2)
    unsigned short* vtg = ws;                  // V^T [32][64][2048] over xn
    unsigned short* qb  = ws + 4194304;        // q|k|v contiguous slots
    unsigned short* kb  = ws + 8388608;
    unsigned short* vb  = ws + 12582912;
    unsigned short* wqt = ws + 16777216;       // [3072][1024] fused Bt
    unsigned short* att = ws + 16777216;       // 4096x1024 bf16 (over WT, dead)
    unsigned short* x1  = ws + 4194304;        // over q (dead after attn)
    unsigned short* wot = ws + 8388608;        // over k (dead after attn)
    unsigned short* w1t = ws + 8388608;        // 2048x1024 bf16 (over WoT, dead)
    unsigned short* w2t = ws + 10485760;       // 1024x2048 bf16
    unsigned short* hb  = ws + 12582912;       // 4096x2048 bf16 (over v+att, dead)
    float* biasf = (float*)(ws + 19922944);    // f32[3072] fused QKV bias

    dim3 gT64(16, 16);                 // 1024x1024 transpose
    dim3 gE(EDIM / 64, BT / 128);      // (16,32) BN=64 gemms
    dim3 gQKV(3072 / 128, BT / 128);   // (24,32) fused QKV BN=128
    dim3 gF(2048 / 128, BT / 128);     // (16,32) FF1 halves BN=128

    // weight transposes for phase 1 (wqt/wkt/wvt contiguous), one launch
    transpose_qkv3_kernel<<<dim3(16, 16, 3), 256, 0, stream>>>(Wq, Wk, Wv, wqt);
    bias_fuse_kernel<<<dim3(12), 256, 0, stream>>>(bq, bk, bv, biasf);

    // LN1 -> xn (fused stats+apply)
    ln_fused_kernel<1><<<BT, 256, 0, stream>>>(x, g1, be1, xn);

    // fused QKV: one gemm, N=3072, BN=128, single-buffered (3 blocks/CU)
    gemm_bt_kernel<V_QKV, 128, 0><<<gQKV, 256, 0, stream>>>(xn, wqt, biasf, nullptr, qb, 3072, EDIM);

    // V^T once per head (xn dead from here until LN2 rewrites it)
    vtrans_kernel<<<dim3(NH * 2, TLEN / 64), 256, 0, stream>>>(vb, vtg);

    attn_kernel<<<dim3(1024), 256, 0, stream>>>(qb, kb, vtg, att);

    // WO (+resid x f32) -> x1 bf16  (2-phase dbuf)
    transpose_kernel<0><<<gT64, 256, 0, stream>>>(Wo, wot, EDIM, EDIM);
    gemm_bt_kernel<V_WO, 64, 1><<<gE, 256, 0, stream>>>(att, wot, bo, x, x1, EDIM, EDIM);

    // LN2 -> xn2 (same slot as xn, fused stats+apply)
    ln_fused_kernel<0><<<BT, 256, 0, stream>>>(x1, g2, be2, xn);

    // FFN, split-K x2 to fit ws: h half = [4096][2048]
    // half A: W1[:, 0:2048], W2[0:2048, :]  (both transposes in one launch)
    transpose_ffn_kernel<<<dim3(32, 16, 2), 256, 0, stream>>>(W1, W2, w1t, w2t);
    gemm_bt_kernel<V_FF1, 128, 1><<<gF, 256, 0, stream>>>(xn, w1t, b1, nullptr, hb, 2048, EDIM);
    gemm_bt_kernel<V_FF2A, 64, 1><<<gE, 256, 0, stream>>>(hb, w2t, nullptr, nullptr, d_out, EDIM, 2048);
    // half B: W1[:, 2048:4096], W2[2048:4096, :]
    transpose_ffn_kernel<<<dim3(32, 16, 2), 256, 0, stream>>>(W1 + 2048, W2 + (size_t)2048 * EDIM, w1t, w2t);
    gemm_bt_kernel<V_FF1, 128, 1><<<gF, 256, 0, stream>>>(xn, w1t, b1 + 2048, nullptr, hb, 2048, EDIM);
    gemm_bt_kernel<V_FF2B, 64, 1><<<gE, 256, 0, stream>>>(hb, w2t, b2, x1, d_out, EDIM, 2048);
}

// Round 10
// 418.328 us; speedup vs baseline: 1.1601x; 1.1601x over previous
//
#include <hip/hip_runtime.h>
#include <stdint.h>

// ---------- problem constants ----------
// WORLD MODEL: external inputs and d_out are FLOAT32 (ref is jnp.float32).
// Internal activations/weights bf16 for MFMA. Threshold 0.125 covers bf16.
#define BT    4096   // B*T
#define EDIM  1024
#define TLEN  2048
#define NH    16
#define DHH   64
#define DFFN  4096

typedef short short8 __attribute__((ext_vector_type(8)));
typedef float f32x4  __attribute__((ext_vector_type(4)));

typedef const __attribute__((address_space(1))) unsigned int* gas_ptr;
typedef __attribute__((address_space(3))) unsigned int*       las_ptr;

__device__ __forceinline__ float bf2f(unsigned short u) {
    union { unsigned int i; float f; } c; c.i = ((unsigned int)u) << 16; return c.f;
}
__device__ __forceinline__ unsigned short f2bf(float f) {
    union { float f; unsigned int i; } c; c.f = f;
    unsigned int u = c.i;
    unsigned int r = u + 0x7fffu + ((u >> 16) & 1u);   // RNE
    return (unsigned short)(r >> 16);
}
__device__ __forceinline__ unsigned short f2bf_trunc(float f) {
    union { float f; unsigned int i; } c; c.f = f;    // truncate: P-only (cheap)
    return (unsigned short)(c.i >> 16);
}
__device__ __forceinline__ float fexp2(float x) {
#if __has_builtin(__builtin_amdgcn_exp2f)
    return __builtin_amdgcn_exp2f(x);
#else
    return __expf(x * 0.69314718056f);
#endif
}
// async global->LDS 16B: per-lane global src, wave-uniform LDS base + lane*16.
__device__ __forceinline__ void gload16(const unsigned short* g, unsigned short* l) {
    __builtin_amdgcn_global_load_lds((gas_ptr)g, (las_ptr)l, 16, 0, 0);
}

// ---------------- weight transpose: f32 [K][N] -> bf16 [N][K] ----------------
// grid: (Nout/64, Kdim/64), 256 threads, 64x64 f32 tile in LDS.
template<int QKV>
__global__ __launch_bounds__(256) void transpose_kernel(
    const float* src, unsigned short* dst, int Kdim, int srcStride)
{
    __shared__ float T[64][65];
    int t = threadIdx.x;
    int n0 = blockIdx.x * 64, k0 = blockIdx.y * 64;
    int r = t >> 4, c4 = (t & 15) * 4;
    #pragma unroll
    for (int i = 0; i < 4; i++) {
        int rr = r + i * 16;
        const float* p;
        if (QKV) p = src + ((size_t)(n0 >> 6)) * 65536 + (size_t)(k0 + rr) * 64 + c4;
        else     p = src + (size_t)(k0 + rr) * srcStride + n0 + c4;
        float4 v = *(const float4*)p;
        T[c4 + 0][rr] = v.x;
        T[c4 + 1][rr] = v.y;
        T[c4 + 2][rr] = v.z;
        T[c4 + 3][rr] = v.w;
    }
    __syncthreads();
    int rn = t >> 2, ck = (t & 3) * 16;
    short8 o0, o1;
    #pragma unroll
    for (int j = 0; j < 8; j++) o0[j] = (short)f2bf(T[rn][ck + j]);
    #pragma unroll
    for (int j = 0; j < 8; j++) o1[j] = (short)f2bf(T[rn][ck + 8 + j]);
    unsigned short* dp = dst + (size_t)(n0 + rn) * Kdim + k0 + ck;
    *(short8*)dp       = o0;
    *(short8*)(dp + 8) = o1;
}

// ---------------- combined Wq/Wk/Wv transpose (grid.z = 3) -------------------
__global__ __launch_bounds__(256) void transpose_qkv3_kernel(
    const float* __restrict__ Wq, const float* __restrict__ Wk,
    const float* __restrict__ Wv, unsigned short* __restrict__ dstbase)
{
    __shared__ float T[64][65];
    int z = blockIdx.z;
    const float* src = (z == 0) ? Wq : (z == 1) ? Wk : Wv;
    unsigned short* dst = dstbase + (size_t)z * 1048576;
    int t = threadIdx.x;
    int n0 = blockIdx.x * 64, k0 = blockIdx.y * 64;
    int r = t >> 4, c4 = (t & 15) * 4;
    #pragma unroll
    for (int i = 0; i < 4; i++) {
        int rr = r + i * 16;
        const float* p = src + ((size_t)(n0 >> 6)) * 65536 + (size_t)(k0 + rr) * 64 + c4;
        float4 v = *(const float4*)p;
        T[c4 + 0][rr] = v.x;
        T[c4 + 1][rr] = v.y;
        T[c4 + 2][rr] = v.z;
        T[c4 + 3][rr] = v.w;
    }
    __syncthreads();
    int rn = t >> 2, ck = (t & 3) * 16;
    short8 o0, o1;
    #pragma unroll
    for (int j = 0; j < 8; j++) o0[j] = (short)f2bf(T[rn][ck + j]);
    #pragma unroll
    for (int j = 0; j < 8; j++) o1[j] = (short)f2bf(T[rn][ck + 8 + j]);
    unsigned short* dp = dst + (size_t)(n0 + rn) * EDIM + k0 + ck;
    *(short8*)dp       = o0;
    *(short8*)(dp + 8) = o1;
}

// ------------- combined FFN-half transpose: W1 slice + W2 slice (z=2) --------
__global__ __launch_bounds__(256) void transpose_ffn_kernel(
    const float* __restrict__ W1h, const float* __restrict__ W2h,
    unsigned short* __restrict__ w1t, unsigned short* __restrict__ w2t)
{
    __shared__ float T[64][65];
    int z = blockIdx.z;
    const float* src;
    unsigned short* dst;
    int Kdim, sstride, n0, k0;
    if (z == 0) { src = W1h; dst = w1t; Kdim = 1024; sstride = 4096;
                  n0 = blockIdx.x * 64; k0 = blockIdx.y * 64; }
    else        { src = W2h; dst = w2t; Kdim = 2048; sstride = 1024;
                  n0 = blockIdx.y * 64; k0 = blockIdx.x * 64; }
    int t = threadIdx.x;
    int r = t >> 4, c4 = (t & 15) * 4;
    #pragma unroll
    for (int i = 0; i < 4; i++) {
        int rr = r + i * 16;
        const float* p = src + (size_t)(k0 + rr) * sstride + n0 + c4;
        float4 v = *(const float4*)p;
        T[c4 + 0][rr] = v.x;
        T[c4 + 1][rr] = v.y;
        T[c4 + 2][rr] = v.z;
        T[c4 + 3][rr] = v.w;
    }
    __syncthreads();
    int rn = t >> 2, ck = (t & 3) * 16;
    short8 o0, o1;
    #pragma unroll
    for (int j = 0; j < 8; j++) o0[j] = (short)f2bf(T[rn][ck + j]);
    #pragma unroll
    for (int j = 0; j < 8; j++) o1[j] = (short)f2bf(T[rn][ck + 8 + j]);
    unsigned short* dp = dst + (size_t)(n0 + rn) * Kdim + k0 + ck;
    *(short8*)dp       = o0;
    *(short8*)(dp + 8) = o1;
}

// ---------------- V transpose: bf16 [bh][2048][64] -> bf16 [bh][64][2048] ----
__global__ __launch_bounds__(256) void vtrans_kernel(
    const unsigned short* __restrict__ v, unsigned short* __restrict__ vt)
{
    __shared__ __align__(16) unsigned short T[64][72];
    int bh = blockIdx.x, st = blockIdx.y;
    int t = threadIdx.x;
    int r = t >> 2, c = (t & 3) * 16;
    const unsigned short* src = v + ((size_t)bh * TLEN + st * 64) * DHH;
    short8 a0 = *(const short8*)(src + r * DHH + c);
    short8 a1 = *(const short8*)(src + r * DHH + c + 8);
    *(short8*)&T[r][c]     = a0;
    *(short8*)&T[r][c + 8] = a1;
    __syncthreads();
    int d = t >> 2;
    short8 o0, o1;
    #pragma unroll
    for (int j = 0; j < 8; j++) o0[j] = (short)T[c + j][d];
    #pragma unroll
    for (int j = 0; j < 8; j++) o1[j] = (short)T[c + 8 + j][d];
    unsigned short* dst = vt + ((size_t)bh * DHH + d) * TLEN + st * 64 + c;
    *(short8*)dst       = o0;
    *(short8*)(dst + 8) = o1;
}

// ---------------- fused QKV bias: [bq|bk|bv] -> f32[3072] ----------------
__global__ __launch_bounds__(256) void bias_fuse_kernel(
    const float* __restrict__ bq, const float* __restrict__ bk,
    const float* __restrict__ bv, float* __restrict__ dst)
{
    int t = blockIdx.x * 256 + threadIdx.x;           // grid 12 -> 3072
    const float* src = (t < 1024) ? bq : (t < 2048) ? bk : bv;
    dst[t] = src[t & 1023];
}

// ---------------- fused LN (stats + apply in one pass) -----------------------
template<int F32IN>
__global__ __launch_bounds__(256) void ln_fused_kernel(
    const void* __restrict__ x, const float* __restrict__ g,
    const float* __restrict__ b, unsigned short* __restrict__ out)
{
    int row = blockIdx.x, tid = threadIdx.x;
    size_t off = (size_t)row * EDIM + tid * 4;
    float v0, v1, v2, v3;
    if (F32IN) {
        float4 a = *(const float4*)((const float*)x + off);
        v0 = a.x; v1 = a.y; v2 = a.z; v3 = a.w;
    } else {
        ushort4 raw = *(const ushort4*)((const unsigned short*)x + off);
        v0 = bf2f(raw.x); v1 = bf2f(raw.y); v2 = bf2f(raw.z); v3 = bf2f(raw.w);
    }
    float s  = v0 + v1 + v2 + v3;
    float ss = v0*v0 + v1*v1 + v2*v2 + v3*v3;
    #pragma unroll
    for (int o = 1; o < 64; o <<= 1) {
        s  += __shfl_xor(s,  o, 64);
        ss += __shfl_xor(ss, o, 64);
    }
    __shared__ float red[8];
    int wave = tid >> 6;
    if ((tid & 63) == 0) { red[wave*2] = s; red[wave*2+1] = ss; }
    __syncthreads();
    s  = red[0] + red[2] + red[4] + red[6];
    ss = red[1] + red[3] + red[5] + red[7];
    float m  = s * (1.0f / EDIM);
    float rs = rsqrtf(ss * (1.0f / EDIM) - m * m + 1e-5f);
    float4 gv = *(const float4*)(g + tid * 4);
    float4 bv = *(const float4*)(b + tid * 4);
    ushort4 o;
    o.x = f2bf((v0 - m) * rs * gv.x + bv.x);
    o.y = f2bf((v1 - m) * rs * gv.y + bv.y);
    o.z = f2bf((v2 - m) * rs * gv.z + bv.z);
    o.w = f2bf((v3 - m) * rs * gv.w + bv.w);
    *(ushort4*)(out + off) = o;
}

// ---------------- gemm_bt: C = A[M][K] x B[N][K]^T, both bf16 ----------------
// BM=128, BK=64, BN template (128 or 64). 4 waves in 2x2.
// global_load_lds (width 16) staging into LINEAR LDS tiles (m97 structure).
// R8 lesson: 2-phase dbuf graft regressed (+50us) -- runtime buffer index
// defeats immediate-offset addressing and the barrier still drains vmcnt(0).
// Proven single-buffer structure (R6, 433.5us) retained.
#define V_QKV  0
#define V_WO   1
#define V_FF1  2
#define V_FF2A 3
#define V_FF2B 4

template<int VARIANT, int BN>
__global__ __launch_bounds__(256) void gemm_bt_kernel(
    const unsigned short* A,        // bf16 [M][K]
    const unsigned short* Bt,       // bf16 [N][K] (transposed weight)
    const float* bias,              // f32 (not read for FF2A)
    const void* resid,              // WO: f32 x ; FF2B: bf16 x1 ; else unused
    void* out,                      // FF2A/B: f32 d_out ; else bf16
    int N, int K)
{
    constexpr int NJ = BN / 32;     // also = B-tile gload issues per thread
    __shared__ __align__(16) unsigned short As[128 * 64];
    __shared__ __align__(16) unsigned short Bs[BN * 64];
    int tid  = threadIdx.x;
    int lane = tid & 63, wave = tid >> 6;
    int quad = lane >> 4, l16 = lane & 15;
    int wr = wave >> 1, wc = wave & 1;
    int m0 = blockIdx.y * 128, n0 = blockIdx.x * BN;

    f32x4 acc[4][NJ];
    #pragma unroll
    for (int i = 0; i < 4; i++)
        #pragma unroll
        for (int j = 0; j < NJ; j++) acc[i][j] = (f32x4){0.f, 0.f, 0.f, 0.f};

    // staging geometry: one wave-issue covers 1024B = 8 rows of 128B (64 elems)
    int lr = lane >> 3;            // row within 8-row stripe
    int lc = (lane & 7) * 8;       // col elems (16B units)

    for (int k0 = 0; k0 < K; k0 += 64) {
        #pragma unroll
        for (int i = 0; i < 4; i++) {
            int r = (i * 4 + wave) * 8 + lr;
            gload16(A + (size_t)(m0 + r) * K + k0 + lc, &As[(i * 4 + wave) * 512]);
        }
        #pragma unroll
        for (int i = 0; i < NJ; i++) {
            int r = (i * 4 + wave) * 8 + lr;
            gload16(Bt + (size_t)(n0 + r) * K + k0 + lc, &Bs[(i * 4 + wave) * 512]);
        }
        __syncthreads();           // vmcnt(0) drain: tile ready

        #pragma unroll
        for (int ks = 0; ks < 2; ks++) {
            short8 af[4], bf[NJ];
            #pragma unroll
            for (int i = 0; i < 4; i++)
                af[i] = *(const short8*)(&As[(wr * 64 + i * 16 + l16) * 64 + ks * 32 + quad * 8]);
            #pragma unroll
            for (int j = 0; j < NJ; j++)
                bf[j] = *(const short8*)(&Bs[(wc * (BN / 2) + j * 16 + l16) * 64 + ks * 32 + quad * 8]);
            #pragma unroll
            for (int i = 0; i < 4; i++)
                #pragma unroll
                for (int j = 0; j < NJ; j++)
                    acc[i][j] = __builtin_amdgcn_mfma_f32_16x16x32_bf16(af[i], bf[j], acc[i][j], 0, 0, 0);
        }

        __syncthreads();           // readers done before next stage overwrites
    }

    // epilogue: row = m0+wr*64+i*16+quad*4+r ; col = n0+wc*(BN/2)+j*16+l16
    #pragma unroll
    for (int j = 0; j < NJ; j++) {
        int c = n0 + wc * (BN / 2) + j * 16 + l16;
        float bi = (VARIANT == V_FF2A) ? 0.0f : bias[c];
        #pragma unroll
        for (int i = 0; i < 4; i++) {
            #pragma unroll
            for (int r = 0; r < 4; r++) {
                int m = m0 + wr * 64 + i * 16 + quad * 4 + r;
                float val = acc[i][j][r] + bi;
                if (VARIANT == V_WO)
                    val += ((const float*)resid)[(size_t)m * N + c];
                if (VARIANT == V_FF2B)
                    val += bf2f(((const unsigned short*)resid)[(size_t)m * N + c])
                         + ((const float*)out)[(size_t)m * N + c];   // partial from FF2A
                if (VARIANT == V_FF1)
                    val = fmaxf(val, 0.0f);
                if (VARIANT == V_QKV) {
                    int b = m >> 11, t = m & 2047;
                    int mat = c >> 10, cc = c & 1023;
                    int h = cc >> 6, d = cc & 63;
                    ((unsigned short*)out)[(size_t)mat * 4194304 +
                        (((size_t)(b * NH + h)) * TLEN + t) * DHH + d] = f2bf(val);
                } else if (VARIANT == V_FF2A || VARIANT == V_FF2B) {
                    ((float*)out)[(size_t)m * N + c] = val;
                } else {
                    ((unsigned short*)out)[(size_t)m * N + c] = f2bf(val);
                }
            }
        }
    }
}

// ---------------- flash attention v7: balanced tile pairing ------------------
// v4.1 counters: Occupancy 14% AVG despite 37.5% LDS cap -- triangular work
// distribution leaves a drain tail. v7: 512 blocks; each block processes TWO
// q-tiles SEQUENTIALLY: qt=p and qt=31-p -> exactly 33 chunk-units per block,
// zero tail, 2 blocks/CU (8 waves) sustained. Per-wave register state is
// REUSED across the two tiles (o/m/l reset) -- no VGPR increase (R5 lesson).
// Barrier structure unchanged; nch block-uniform within each half.
__global__ __launch_bounds__(256) void attn_kernel(
    const unsigned short* __restrict__ q,
    const unsigned short* __restrict__ k,
    const unsigned short* __restrict__ vt,   // [bh][64 d][2048 s]
    unsigned short* __restrict__ att)
{
    __shared__ __align__(16) unsigned short Ks[128 * 72];     // 18.0 KB
    __shared__ __align__(16) unsigned short Vs[64 * 136];     // 17.0 KB
    __shared__ __align__(16) unsigned short Ps[4][16 * 136];  // 17.0 KB
    int tid  = threadIdx.x;
    int lane = tid & 63, wave = tid >> 6;
    int quad = lane >> 4, l16 = lane & 15;

    int flat = blockIdx.x;               // 0..511
    int xcd  = flat & 7, idx = flat >> 3;
    int bh   = xcd * 4 + (idx >> 4);     // 4 heads per XCD
    int pp   = idx & 15;                 // pair index: tiles pp and 31-pp

    const unsigned short* Kb = k  + (size_t)bh * TLEN * DHH;
    const unsigned short* Vb = vt + (size_t)bh * DHH * TLEN;
    unsigned short* Pw = Ps[wave];
    const float cs = 0.18033688011f;     // 0.125 * log2(e)

    int rowK = tid >> 1, colK = (tid & 1) * 32;
    int rowV = tid >> 2, colV = (tid & 3) * 32;
    int bidx = bh >> 4, hh = bh & 15;

    for (int half = 0; half < 2; ++half) {
        int qt = half ? (31 - pp) : pp;
        int q0 = qt * 64;
        int qw = q0 + wave * 16;         // this wave's 16 q-rows

        const unsigned short* Qb = q + ((size_t)bh * TLEN + qw) * DHH;
        short8 aq0 = *(const short8*)(Qb + l16 * DHH + quad * 8);
        short8 aq1 = *(const short8*)(Qb + l16 * DHH + 32 + quad * 8);

        f32x4 o[4];
        #pragma unroll
        for (int n = 0; n < 4; n++) o[n] = (f32x4){0.f, 0.f, 0.f, 0.f};
        f32x4 mrow = {-1e30f, -1e30f, -1e30f, -1e30f};
        f32x4 lrow = {0.f, 0.f, 0.f, 0.f};   // per-lane partial denominator

        int nch = (q0 >> 7) + 1;         // block-uniform (exact for all waves)

        // prefetch chunk 0 into registers
        short8 ka0, ka1, ka2, ka3, va0, va1, va2, va3;
        {
            const unsigned short* kp = Kb + (size_t)rowK * DHH + colK;
            ka0 = *(const short8*)kp;
            ka1 = *(const short8*)(kp + 8);
            ka2 = *(const short8*)(kp + 16);
            ka3 = *(const short8*)(kp + 24);
            const unsigned short* vp = Vb + (size_t)rowV * TLEN + colV;
            va0 = *(const short8*)vp;
            va1 = *(const short8*)(vp + 8);
            va2 = *(const short8*)(vp + 16);
            va3 = *(const short8*)(vp + 24);
        }

        for (int ch = 0; ch < nch; ch++) {
            int s0 = ch * 128;
            __syncthreads();             // all waves done reading prior chunk
            *(short8*)(&Ks[rowK * 72 + colK])       = ka0;
            *(short8*)(&Ks[rowK * 72 + colK + 8])   = ka1;
            *(short8*)(&Ks[rowK * 72 + colK + 16])  = ka2;
            *(short8*)(&Ks[rowK * 72 + colK + 24])  = ka3;
            *(short8*)(&Vs[rowV * 136 + colV])      = va0;
            *(short8*)(&Vs[rowV * 136 + colV + 8])  = va1;
            *(short8*)(&Vs[rowV * 136 + colV + 16]) = va2;
            *(short8*)(&Vs[rowV * 136 + colV + 24]) = va3;
            __syncthreads();             // staged

            if (ch + 1 < nch) {          // T14: next chunk's loads hide here
                int s1 = s0 + 128;
                const unsigned short* kp = Kb + (size_t)(s1 + rowK) * DHH + colK;
                ka0 = *(const short8*)kp;
                ka1 = *(const short8*)(kp + 8);
                ka2 = *(const short8*)(kp + 16);
                ka3 = *(const short8*)(kp + 24);
                const unsigned short* vp = Vb + (size_t)rowV * TLEN + s1 + colV;
                va0 = *(const short8*)vp;
                va1 = *(const short8*)(vp + 8);
                va2 = *(const short8*)(vp + 16);
                va3 = *(const short8*)(vp + 24);
            }

            // ---- QK^T: S[q 16][s 128] ----
            f32x4 S[8];
            #pragma unroll
            for (int n = 0; n < 8; n++) {
                short8 b0 = *(const short8*)(&Ks[(n * 16 + l16) * 72 + quad * 8]);
                short8 b1 = *(const short8*)(&Ks[(n * 16 + l16) * 72 + 32 + quad * 8]);
                f32x4 s = (f32x4){0.f, 0.f, 0.f, 0.f};
                s = __builtin_amdgcn_mfma_f32_16x16x32_bf16(aq0, b0, s, 0, 0, 0);
                s = __builtin_amdgcn_mfma_f32_16x16x32_bf16(aq1, b1, s, 0, 0, 0);
                S[n] = s;
            }
            bool needmask = (s0 + 127 > qw);  // wave-uniform; diag chunk(s)
            // ---- online softmax (exp2 domain) ----
            #pragma unroll
            for (int r = 0; r < 4; r++) {
                float xv[8];
                #pragma unroll
                for (int n = 0; n < 8; n++) {
                    float xx = S[n][r] * cs;
                    if (needmask && (s0 + n * 16 + l16 > qw + quad * 4 + r)) xx = -1e30f;
                    xv[n] = xx;
                }
                float mxl = fmaxf(fmaxf(fmaxf(xv[0], xv[1]), fmaxf(xv[2], xv[3])),
                                  fmaxf(fmaxf(xv[4], xv[5]), fmaxf(xv[6], xv[7])));
                float used;
                if (__all(mxl <= mrow[r] + 8.0f)) {       // defer-rescale (T13)
                    used = mrow[r];
                } else {
                    float mx = mxl;
                    mx = fmaxf(mx, __shfl_xor(mx, 1, 64));
                    mx = fmaxf(mx, __shfl_xor(mx, 2, 64));
                    mx = fmaxf(mx, __shfl_xor(mx, 4, 64));
                    mx = fmaxf(mx, __shfl_xor(mx, 8, 64));
                    float mnew  = fmaxf(mrow[r], mx);
                    float alpha = fexp2(mrow[r] - mnew);
                    lrow[r] *= alpha;
                    o[0][r] *= alpha; o[1][r] *= alpha;
                    o[2][r] *= alpha; o[3][r] *= alpha;
                    mrow[r] = mnew;
                    used = mnew;
                }
                float ps = 0.f;
                int prow = (quad * 4 + r) * 136;
                #pragma unroll
                for (int n = 0; n < 8; n++) {
                    float p = fexp2(xv[n] - used);
                    ps += p;
                    Pw[prow + n * 16 + l16] = f2bf_trunc(p);
                }
                lrow[r] += ps;
            }
            // ---- PV: O += P[16x128] * V[128x64] ----
            short8 ap[4];
            #pragma unroll
            for (int ks = 0; ks < 4; ks++)
                ap[ks] = *(const short8*)(Pw + l16 * 136 + ks * 32 + quad * 8);
            #pragma unroll
            for (int n = 0; n < 4; n++) {
                #pragma unroll
                for (int ks = 0; ks < 4; ks++) {
                    short8 b = *(const short8*)(&Vs[(n * 16 + l16) * 136 + ks * 32 + quad * 8]);
                    o[n] = __builtin_amdgcn_mfma_f32_16x16x32_bf16(ap[ks], b, o[n], 0, 0, 0);
                }
            }
        }

        // ---- output this tile ----
        #pragma unroll
        for (int r = 0; r < 4; r++) {
            float ls = lrow[r];
            ls += __shfl_xor(ls, 1, 64);
            ls += __shfl_xor(ls, 2, 64);
            ls += __shfl_xor(ls, 4, 64);
            ls += __shfl_xor(ls, 8, 64);
            float inv = 1.0f / ls;
            int t = qw + quad * 4 + r;
            size_t rowoff = ((size_t)(bidx * TLEN + t)) * EDIM + hh * 64;
            #pragma unroll
            for (int n = 0; n < 4; n++)
                att[rowoff + n * 16 + l16] = f2bf(o[n][r] * inv);
        }
    }
}

// ---------------- launcher ----------------
extern "C" void kernel_launch(void* const* d_in, const int* in_sizes, int n_in,
                              void* d_out, int out_size, void* d_ws, size_t ws_size,
                              hipStream_t stream)
{
    (void)in_sizes; (void)n_in; (void)out_size; (void)ws_size;
    const float* x   = (const float*)d_in[0];
    const float* Wq  = (const float*)d_in[1];
    const float* bq  = (const float*)d_in[2];
    const float* Wk  = (const float*)d_in[3];
    const float* bk  = (const float*)d_in[4];
    const float* Wv  = (const float*)d_in[5];
    const float* bv  = (const float*)d_in[6];
    const float* Wo  = (const float*)d_in[7];
    const float* bo  = (const float*)d_in[8];
    const float* W1  = (const float*)d_in[9];
    const float* b1  = (const float*)d_in[10];
    const float* W2  = (const float*)d_in[11];
    const float* b2  = (const float*)d_in[12];
    const float* g1  = (const float*)d_in[13];
    const float* be1 = (const float*)d_in[14];
    const float* g2  = (const float*)d_in[15];
    const float* be2 = (const float*)d_in[16];

    // ws layout (ushort elems; total byte use < proven 42,008,640):
    //   xn/vtg/xn2 bytes 0..8M | q 8..16M (later x1) | k 16..24M (later WoT/W1T
    //   16..20M, W2T 20..24M) | v 24..32M | WqT/WkT/WvT 32..38M (contiguous
    //   [3072][1024] for fused QKV) then att 32..40M | biasf @ elem 19922944
    //   (byte 39,845,888; live only during QKV, att overwrites later) |
    //   h 24..40M (over v+att)
    unsigned short* ws  = (unsigned short*)d_ws;
    unsigned short* xn  = ws;                  // 4096x1024 bf16 (xn, vtg, xn2)
    unsigned short* vtg = ws;                  // V^T [32][64][2048] over xn
    unsigned short* qb  = ws + 4194304;        // q|k|v contiguous slots
    unsigned short* kb  = ws + 8388608;
    unsigned short* vb  = ws + 12582912;
    unsigned short* wqt = ws + 16777216;       // [3072][1024] fused Bt
    unsigned short* att = ws + 16777216;       // 4096x1024 bf16 (over WT, dead)
    unsigned short* x1  = ws + 4194304;        // over q (dead after attn)
    unsigned short* wot = ws + 8388608;        // over k (dead after attn)
    unsigned short* w1t = ws + 8388608;        // 2048x1024 bf16 (over WoT, dead)
    unsigned short* w2t = ws + 10485760;       // 1024x2048 bf16
    unsigned short* hb  = ws + 12582912;       // 4096x2048 bf16 (over v+att, dead)
    float* biasf = (float*)(ws + 19922944);    // f32[3072] fused QKV bias

    dim3 gT64(16, 16);                 // 1024x1024 transpose
    dim3 gE(EDIM / 64, BT / 128);      // (16,32) BN=64 gemms
    dim3 gQKV(3072 / 128, BT / 128);   // (24,32) fused QKV BN=128
    dim3 gF(2048 / 128, BT / 128);     // (16,32) FF1 halves BN=128

    // weight transposes for phase 1 (wqt/wkt/wvt contiguous), one launch
    transpose_qkv3_kernel<<<dim3(16, 16, 3), 256, 0, stream>>>(Wq, Wk, Wv, wqt);
    bias_fuse_kernel<<<dim3(12), 256, 0, stream>>>(bq, bk, bv, biasf);

    // LN1 -> xn (fused stats+apply)
    ln_fused_kernel<1><<<BT, 256, 0, stream>>>(x, g1, be1, xn);

    // fused QKV: one gemm, N=3072, BN=128
    gemm_bt_kernel<V_QKV, 128><<<gQKV, 256, 0, stream>>>(xn, wqt, biasf, nullptr, qb, 3072, EDIM);

    // V^T once per head (xn dead from here until LN2 rewrites it)
    vtrans_kernel<<<dim3(NH * 2, TLEN / 64), 256, 0, stream>>>(vb, vtg);

    attn_kernel<<<dim3(512), 256, 0, stream>>>(qb, kb, vtg, att);

    // WO (+resid x f32) -> x1 bf16
    transpose_kernel<0><<<gT64, 256, 0, stream>>>(Wo, wot, EDIM, EDIM);
    gemm_bt_kernel<V_WO, 64><<<gE, 256, 0, stream>>>(att, wot, bo, x, x1, EDIM, EDIM);

    // LN2 -> xn2 (same slot as xn, fused stats+apply)
    ln_fused_kernel<0><<<BT, 256, 0, stream>>>(x1, g2, be2, xn);

    // FFN, split-K x2 to fit ws: h half = [4096][2048]
    // half A: W1[:, 0:2048], W2[0:2048, :]  (both transposes in one launch)
    transpose_ffn_kernel<<<dim3(32, 16, 2), 256, 0, stream>>>(W1, W2, w1t, w2t);
    gemm_bt_kernel<V_FF1, 128><<<gF, 256, 0, stream>>>(xn, w1t, b1, nullptr, hb, 2048, EDIM);
    gemm_bt_kernel<V_FF2A, 64><<<gE, 256, 0, stream>>>(hb, w2t, nullptr, nullptr, d_out, EDIM, 2048);
    // half B: W1[:, 2048:4096], W2[2048:4096, :]
    transpose_ffn_kernel<<<dim3(32, 16, 2), 256, 0, stream>>>(W1 + 2048, W2 + (size_t)2048 * EDIM, w1t, w2t);
    gemm_bt_kernel<V_FF1, 128><<<gF, 256, 0, stream>>>(xn, w1t, b1 + 2048, nullptr, hb, 2048, EDIM);
    gemm_bt_kernel<V_FF2B, 64><<<gE, 256, 0, stream>>>(hb, w2t, b2, x1, d_out, EDIM, 2048);
}

// Round 11
// 410.393 us; speedup vs baseline: 1.1826x; 1.0193x over previous
//
#include <hip/hip_runtime.h>
#include <stdint.h>

// ---------- problem constants ----------
// WORLD MODEL: external inputs and d_out are FLOAT32 (ref is jnp.float32).
// Internal activations/weights bf16 for MFMA. Threshold 0.125 covers bf16.
#define BT    4096   // B*T
#define EDIM  1024
#define TLEN  2048
#define NH    16
#define DHH   64
#define DFFN  4096

typedef short short8 __attribute__((ext_vector_type(8)));
typedef float f32x4  __attribute__((ext_vector_type(4)));

typedef const __attribute__((address_space(1))) unsigned int* gas_ptr;
typedef __attribute__((address_space(3))) unsigned int*       las_ptr;

__device__ __forceinline__ float bf2f(unsigned short u) {
    union { unsigned int i; float f; } c; c.i = ((unsigned int)u) << 16; return c.f;
}
__device__ __forceinline__ unsigned short f2bf(float f) {
    union { float f; unsigned int i; } c; c.f = f;
    unsigned int u = c.i;
    unsigned int r = u + 0x7fffu + ((u >> 16) & 1u);   // RNE
    return (unsigned short)(r >> 16);
}
__device__ __forceinline__ unsigned short f2bf_trunc(float f) {
    union { float f; unsigned int i; } c; c.f = f;    // truncate: P-only (cheap)
    return (unsigned short)(c.i >> 16);
}
__device__ __forceinline__ float fexp2(float x) {
#if __has_builtin(__builtin_amdgcn_exp2f)
    return __builtin_amdgcn_exp2f(x);
#else
    return __expf(x * 0.69314718056f);
#endif
}
// async global->LDS 16B: per-lane global src, wave-uniform LDS base + lane*16.
__device__ __forceinline__ void gload16(const unsigned short* g, unsigned short* l) {
    __builtin_amdgcn_global_load_lds((gas_ptr)g, (las_ptr)l, 16, 0, 0);
}

#define CS_SCALE 0.18033688011f   // 0.125 * log2(e), folded into Q at QKV epilogue

// ---------------- weight transpose: f32 [K][N] -> bf16 [N][K] ----------------
// grid: (Nout/64, Kdim/64), 256 threads, 64x64 f32 tile in LDS.
template<int QKV>
__global__ __launch_bounds__(256) void transpose_kernel(
    const float* src, unsigned short* dst, int Kdim, int srcStride)
{
    __shared__ float T[64][65];
    int t = threadIdx.x;
    int n0 = blockIdx.x * 64, k0 = blockIdx.y * 64;
    int r = t >> 4, c4 = (t & 15) * 4;
    #pragma unroll
    for (int i = 0; i < 4; i++) {
        int rr = r + i * 16;
        const float* p;
        if (QKV) p = src + ((size_t)(n0 >> 6)) * 65536 + (size_t)(k0 + rr) * 64 + c4;
        else     p = src + (size_t)(k0 + rr) * srcStride + n0 + c4;
        float4 v = *(const float4*)p;
        T[c4 + 0][rr] = v.x;
        T[c4 + 1][rr] = v.y;
        T[c4 + 2][rr] = v.z;
        T[c4 + 3][rr] = v.w;
    }
    __syncthreads();
    int rn = t >> 2, ck = (t & 3) * 16;
    short8 o0, o1;
    #pragma unroll
    for (int j = 0; j < 8; j++) o0[j] = (short)f2bf(T[rn][ck + j]);
    #pragma unroll
    for (int j = 0; j < 8; j++) o1[j] = (short)f2bf(T[rn][ck + 8 + j]);
    unsigned short* dp = dst + (size_t)(n0 + rn) * Kdim + k0 + ck;
    *(short8*)dp       = o0;
    *(short8*)(dp + 8) = o1;
}

// ---------------- combined Wq/Wk/Wv transpose (grid.z = 3) -------------------
__global__ __launch_bounds__(256) void transpose_qkv3_kernel(
    const float* __restrict__ Wq, const float* __restrict__ Wk,
    const float* __restrict__ Wv, unsigned short* __restrict__ dstbase)
{
    __shared__ float T[64][65];
    int z = blockIdx.z;
    const float* src = (z == 0) ? Wq : (z == 1) ? Wk : Wv;
    unsigned short* dst = dstbase + (size_t)z * 1048576;
    int t = threadIdx.x;
    int n0 = blockIdx.x * 64, k0 = blockIdx.y * 64;
    int r = t >> 4, c4 = (t & 15) * 4;
    #pragma unroll
    for (int i = 0; i < 4; i++) {
        int rr = r + i * 16;
        const float* p = src + ((size_t)(n0 >> 6)) * 65536 + (size_t)(k0 + rr) * 64 + c4;
        float4 v = *(const float4*)p;
        T[c4 + 0][rr] = v.x;
        T[c4 + 1][rr] = v.y;
        T[c4 + 2][rr] = v.z;
        T[c4 + 3][rr] = v.w;
    }
    __syncthreads();
    int rn = t >> 2, ck = (t & 3) * 16;
    short8 o0, o1;
    #pragma unroll
    for (int j = 0; j < 8; j++) o0[j] = (short)f2bf(T[rn][ck + j]);
    #pragma unroll
    for (int j = 0; j < 8; j++) o1[j] = (short)f2bf(T[rn][ck + 8 + j]);
    unsigned short* dp = dst + (size_t)(n0 + rn) * EDIM + k0 + ck;
    *(short8*)dp       = o0;
    *(short8*)(dp + 8) = o1;
}

// ------------- combined FFN-half transpose: W1 slice + W2 slice (z=2) --------
__global__ __launch_bounds__(256) void transpose_ffn_kernel(
    const float* __restrict__ W1h, const float* __restrict__ W2h,
    unsigned short* __restrict__ w1t, unsigned short* __restrict__ w2t)
{
    __shared__ float T[64][65];
    int z = blockIdx.z;
    const float* src;
    unsigned short* dst;
    int Kdim, sstride, n0, k0;
    if (z == 0) { src = W1h; dst = w1t; Kdim = 1024; sstride = 4096;
                  n0 = blockIdx.x * 64; k0 = blockIdx.y * 64; }
    else        { src = W2h; dst = w2t; Kdim = 2048; sstride = 1024;
                  n0 = blockIdx.y * 64; k0 = blockIdx.x * 64; }
    int t = threadIdx.x;
    int r = t >> 4, c4 = (t & 15) * 4;
    #pragma unroll
    for (int i = 0; i < 4; i++) {
        int rr = r + i * 16;
        const float* p = src + (size_t)(k0 + rr) * sstride + n0 + c4;
        float4 v = *(const float4*)p;
        T[c4 + 0][rr] = v.x;
        T[c4 + 1][rr] = v.y;
        T[c4 + 2][rr] = v.z;
        T[c4 + 3][rr] = v.w;
    }
    __syncthreads();
    int rn = t >> 2, ck = (t & 3) * 16;
    short8 o0, o1;
    #pragma unroll
    for (int j = 0; j < 8; j++) o0[j] = (short)f2bf(T[rn][ck + j]);
    #pragma unroll
    for (int j = 0; j < 8; j++) o1[j] = (short)f2bf(T[rn][ck + 8 + j]);
    unsigned short* dp = dst + (size_t)(n0 + rn) * Kdim + k0 + ck;
    *(short8*)dp       = o0;
    *(short8*)(dp + 8) = o1;
}

// ---------------- V transpose: bf16 [bh][2048][64] -> bf16 [bh][64][2048] ----
__global__ __launch_bounds__(256) void vtrans_kernel(
    const unsigned short* __restrict__ v, unsigned short* __restrict__ vt)
{
    __shared__ __align__(16) unsigned short T[64][72];
    int bh = blockIdx.x, st = blockIdx.y;
    int t = threadIdx.x;
    int r = t >> 2, c = (t & 3) * 16;
    const unsigned short* src = v + ((size_t)bh * TLEN + st * 64) * DHH;
    short8 a0 = *(const short8*)(src + r * DHH + c);
    short8 a1 = *(const short8*)(src + r * DHH + c + 8);
    *(short8*)&T[r][c]     = a0;
    *(short8*)&T[r][c + 8] = a1;
    __syncthreads();
    int d = t >> 2;
    short8 o0, o1;
    #pragma unroll
    for (int j = 0; j < 8; j++) o0[j] = (short)T[c + j][d];
    #pragma unroll
    for (int j = 0; j < 8; j++) o1[j] = (short)T[c + 8 + j][d];
    unsigned short* dst = vt + ((size_t)bh * DHH + d) * TLEN + st * 64 + c;
    *(short8*)dst       = o0;
    *(short8*)(dst + 8) = o1;
}

// ---------------- fused QKV bias: [bq|bk|bv] -> f32[3072] ----------------
__global__ __launch_bounds__(256) void bias_fuse_kernel(
    const float* __restrict__ bq, const float* __restrict__ bk,
    const float* __restrict__ bv, float* __restrict__ dst)
{
    int t = blockIdx.x * 256 + threadIdx.x;           // grid 12 -> 3072
    const float* src = (t < 1024) ? bq : (t < 2048) ? bk : bv;
    dst[t] = src[t & 1023];
}

// ---------------- fused LN (stats + apply in one pass) -----------------------
template<int F32IN>
__global__ __launch_bounds__(256) void ln_fused_kernel(
    const void* __restrict__ x, const float* __restrict__ g,
    const float* __restrict__ b, unsigned short* __restrict__ out)
{
    int row = blockIdx.x, tid = threadIdx.x;
    size_t off = (size_t)row * EDIM + tid * 4;
    float v0, v1, v2, v3;
    if (F32IN) {
        float4 a = *(const float4*)((const float*)x + off);
        v0 = a.x; v1 = a.y; v2 = a.z; v3 = a.w;
    } else {
        ushort4 raw = *(const ushort4*)((const unsigned short*)x + off);
        v0 = bf2f(raw.x); v1 = bf2f(raw.y); v2 = bf2f(raw.z); v3 = bf2f(raw.w);
    }
    float s  = v0 + v1 + v2 + v3;
    float ss = v0*v0 + v1*v1 + v2*v2 + v3*v3;
    #pragma unroll
    for (int o = 1; o < 64; o <<= 1) {
        s  += __shfl_xor(s,  o, 64);
        ss += __shfl_xor(ss, o, 64);
    }
    __shared__ float red[8];
    int wave = tid >> 6;
    if ((tid & 63) == 0) { red[wave*2] = s; red[wave*2+1] = ss; }
    __syncthreads();
    s  = red[0] + red[2] + red[4] + red[6];
    ss = red[1] + red[3] + red[5] + red[7];
    float m  = s * (1.0f / EDIM);
    float rs = rsqrtf(ss * (1.0f / EDIM) - m * m + 1e-5f);
    float4 gv = *(const float4*)(g + tid * 4);
    float4 bv = *(const float4*)(b + tid * 4);
    ushort4 o;
    o.x = f2bf((v0 - m) * rs * gv.x + bv.x);
    o.y = f2bf((v1 - m) * rs * gv.y + bv.y);
    o.z = f2bf((v2 - m) * rs * gv.z + bv.z);
    o.w = f2bf((v3 - m) * rs * gv.w + bv.w);
    *(ushort4*)(out + off) = o;
}

// ---------------- gemm_bt: C = A[M][K] x B[N][K]^T, both bf16 ----------------
// BM=128 (QKV/FF1). global_load_lds staging, LINEAR LDS, m97 structure.
#define V_QKV  0
#define V_WO   1
#define V_FF1  2
#define V_FF2A 3
#define V_FF2B 4

template<int VARIANT, int BN>
__global__ __launch_bounds__(256) void gemm_bt_kernel(
    const unsigned short* A,        // bf16 [M][K]
    const unsigned short* Bt,       // bf16 [N][K] (transposed weight)
    const float* bias,              // f32
    const void* resid,              // unused here
    void* out,                      // QKV: bf16 q|k|v ; FF1: bf16 h
    int N, int K)
{
    constexpr int NJ = BN / 32;     // also = B-tile gload issues per thread
    __shared__ __align__(16) unsigned short As[128 * 64];
    __shared__ __align__(16) unsigned short Bs[BN * 64];
    int tid  = threadIdx.x;
    int lane = tid & 63, wave = tid >> 6;
    int quad = lane >> 4, l16 = lane & 15;
    int wr = wave >> 1, wc = wave & 1;
    int m0 = blockIdx.y * 128, n0 = blockIdx.x * BN;

    f32x4 acc[4][NJ];
    #pragma unroll
    for (int i = 0; i < 4; i++)
        #pragma unroll
        for (int j = 0; j < NJ; j++) acc[i][j] = (f32x4){0.f, 0.f, 0.f, 0.f};

    // staging geometry: one wave-issue covers 1024B = 8 rows of 128B (64 elems)
    int lr = lane >> 3;            // row within 8-row stripe
    int lc = (lane & 7) * 8;       // col elems (16B units)

    for (int k0 = 0; k0 < K; k0 += 64) {
        #pragma unroll
        for (int i = 0; i < 4; i++) {
            int r = (i * 4 + wave) * 8 + lr;
            gload16(A + (size_t)(m0 + r) * K + k0 + lc, &As[(i * 4 + wave) * 512]);
        }
        #pragma unroll
        for (int i = 0; i < NJ; i++) {
            int r = (i * 4 + wave) * 8 + lr;
            gload16(Bt + (size_t)(n0 + r) * K + k0 + lc, &Bs[(i * 4 + wave) * 512]);
        }
        __syncthreads();           // vmcnt(0) drain: tile ready

        #pragma unroll
        for (int ks = 0; ks < 2; ks++) {
            short8 af[4], bf[NJ];
            #pragma unroll
            for (int i = 0; i < 4; i++)
                af[i] = *(const short8*)(&As[(wr * 64 + i * 16 + l16) * 64 + ks * 32 + quad * 8]);
            #pragma unroll
            for (int j = 0; j < NJ; j++)
                bf[j] = *(const short8*)(&Bs[(wc * (BN / 2) + j * 16 + l16) * 64 + ks * 32 + quad * 8]);
            #pragma unroll
            for (int i = 0; i < 4; i++)
                #pragma unroll
                for (int j = 0; j < NJ; j++)
                    acc[i][j] = __builtin_amdgcn_mfma_f32_16x16x32_bf16(af[i], bf[j], acc[i][j], 0, 0, 0);
        }

        __syncthreads();           // readers done before next stage overwrites
    }

    // epilogue: row = m0+wr*64+i*16+quad*4+r ; col = n0+wc*(BN/2)+j*16+l16
    #pragma unroll
    for (int j = 0; j < NJ; j++) {
        int c = n0 + wc * (BN / 2) + j * 16 + l16;
        float bi = bias[c];
        #pragma unroll
        for (int i = 0; i < 4; i++) {
            #pragma unroll
            for (int r = 0; r < 4; r++) {
                int m = m0 + wr * 64 + i * 16 + quad * 4 + r;
                float val = acc[i][j][r] + bi;
                if (VARIANT == V_FF1)
                    val = fmaxf(val, 0.0f);
                if (VARIANT == V_QKV) {
                    int b = m >> 11, t = m & 2047;
                    int mat = c >> 10, cc = c & 1023;
                    int h = cc >> 6, d = cc & 63;
                    if (mat == 0) val *= CS_SCALE;   // fold softmax scale into Q
                    ((unsigned short*)out)[(size_t)mat * 4194304 +
                        (((size_t)(b * NH + h)) * TLEN + t) * DHH + d] = f2bf(val);
                } else {
                    ((unsigned short*)out)[(size_t)m * N + c] = f2bf(val);
                }
            }
        }
    }
}

// ------------- gemm_bt64: BM=64, BN=64 variant for N=1024 gemms --------------
// WO/FF2A/FF2B at BM=128 were grid-capped at 2 blocks/CU (512 blocks) -- same
// diagnosis as attn pre-R9. BM=64 doubles the grid to 1024 = 4 blocks/CU
// (LDS 16KB, small acc) for 2x the wave-level overlap of the barrier drain.
// B-panels (2-4MB) are XCD-L2-resident; A traffic unchanged (same n-blocks).
template<int VARIANT>
__global__ __launch_bounds__(256) void gemm_bt64_kernel(
    const unsigned short* A,        // bf16 [M][K]
    const unsigned short* Bt,       // bf16 [N][K]
    const float* bias,              // f32 (not read for FF2A)
    const void* resid,              // WO: f32 x ; FF2B: bf16 x1
    void* out,                      // WO: bf16 x1 ; FF2A/B: f32 d_out
    int N, int K)
{
    __shared__ __align__(16) unsigned short As[64 * 64];
    __shared__ __align__(16) unsigned short Bs[64 * 64];
    int tid  = threadIdx.x;
    int lane = tid & 63, wave = tid >> 6;
    int quad = lane >> 4, l16 = lane & 15;
    int wr = wave >> 1, wc = wave & 1;        // 2x2 waves, 32x32 each
    int m0 = blockIdx.y * 64, n0 = blockIdx.x * 64;

    f32x4 acc[2][2];
    #pragma unroll
    for (int i = 0; i < 2; i++)
        #pragma unroll
        for (int j = 0; j < 2; j++) acc[i][j] = (f32x4){0.f, 0.f, 0.f, 0.f};

    int lr = lane >> 3;            // row within 8-row stripe
    int lc = (lane & 7) * 8;       // col elems (16B units)

    for (int k0 = 0; k0 < K; k0 += 64) {
        #pragma unroll
        for (int i = 0; i < 2; i++) {
            int blk = i * 4 + wave;            // 0..7 covers 64 rows
            gload16(A + (size_t)(m0 + blk * 8 + lr) * K + k0 + lc, &As[blk * 512]);
        }
        #pragma unroll
        for (int i = 0; i < 2; i++) {
            int blk = i * 4 + wave;
            gload16(Bt + (size_t)(n0 + blk * 8 + lr) * K + k0 + lc, &Bs[blk * 512]);
        }
        __syncthreads();           // vmcnt(0) drain: tile ready

        #pragma unroll
        for (int ks = 0; ks < 2; ks++) {
            short8 af[2], bf[2];
            #pragma unroll
            for (int i = 0; i < 2; i++)
                af[i] = *(const short8*)(&As[(wr * 32 + i * 16 + l16) * 64 + ks * 32 + quad * 8]);
            #pragma unroll
            for (int j = 0; j < 2; j++)
                bf[j] = *(const short8*)(&Bs[(wc * 32 + j * 16 + l16) * 64 + ks * 32 + quad * 8]);
            #pragma unroll
            for (int i = 0; i < 2; i++)
                #pragma unroll
                for (int j = 0; j < 2; j++)
                    acc[i][j] = __builtin_amdgcn_mfma_f32_16x16x32_bf16(af[i], bf[j], acc[i][j], 0, 0, 0);
        }

        __syncthreads();           // readers done before next stage overwrites
    }

    // epilogue: row = m0+wr*32+i*16+quad*4+r ; col = n0+wc*32+j*16+l16
    #pragma unroll
    for (int j = 0; j < 2; j++) {
        int c = n0 + wc * 32 + j * 16 + l16;
        float bi = (VARIANT == V_FF2A) ? 0.0f : bias[c];
        #pragma unroll
        for (int i = 0; i < 2; i++) {
            #pragma unroll
            for (int r = 0; r < 4; r++) {
                int m = m0 + wr * 32 + i * 16 + quad * 4 + r;
                float val = acc[i][j][r] + bi;
                if (VARIANT == V_WO) {
                    val += ((const float*)resid)[(size_t)m * N + c];
                    ((unsigned short*)out)[(size_t)m * N + c] = f2bf(val);
                } else if (VARIANT == V_FF2A) {
                    ((float*)out)[(size_t)m * N + c] = val;
                } else {  // V_FF2B
                    val += bf2f(((const unsigned short*)resid)[(size_t)m * N + c])
                         + ((const float*)out)[(size_t)m * N + c];
                    ((float*)out)[(size_t)m * N + c] = val;
                }
            }
        }
    }
}

// ---------------- flash attention v7.1: balanced pairing + pre-scaled Q ------
// R9 proven structure (63us). v7.1: Q arrives pre-scaled by 0.125*log2e from
// the QKV epilogue -- the per-element softmax scale multiply is deleted.
__global__ __launch_bounds__(256) void attn_kernel(
    const unsigned short* __restrict__ q,
    const unsigned short* __restrict__ k,
    const unsigned short* __restrict__ vt,   // [bh][64 d][2048 s]
    unsigned short* __restrict__ att)
{
    __shared__ __align__(16) unsigned short Ks[128 * 72];     // 18.0 KB
    __shared__ __align__(16) unsigned short Vs[64 * 136];     // 17.0 KB
    __shared__ __align__(16) unsigned short Ps[4][16 * 136];  // 17.0 KB
    int tid  = threadIdx.x;
    int lane = tid & 63, wave = tid >> 6;
    int quad = lane >> 4, l16 = lane & 15;

    int flat = blockIdx.x;               // 0..511
    int xcd  = flat & 7, idx = flat >> 3;
    int bh   = xcd * 4 + (idx >> 4);     // 4 heads per XCD
    int pp   = idx & 15;                 // pair index: tiles pp and 31-pp

    const unsigned short* Kb = k  + (size_t)bh * TLEN * DHH;
    const unsigned short* Vb = vt + (size_t)bh * DHH * TLEN;
    unsigned short* Pw = Ps[wave];

    int rowK = tid >> 1, colK = (tid & 1) * 32;
    int rowV = tid >> 2, colV = (tid & 3) * 32;
    int bidx = bh >> 4, hh = bh & 15;

    for (int half = 0; half < 2; ++half) {
        int qt = half ? (31 - pp) : pp;
        int q0 = qt * 64;
        int qw = q0 + wave * 16;         // this wave's 16 q-rows

        const unsigned short* Qb = q + ((size_t)bh * TLEN + qw) * DHH;
        short8 aq0 = *(const short8*)(Qb + l16 * DHH + quad * 8);
        short8 aq1 = *(const short8*)(Qb + l16 * DHH + 32 + quad * 8);

        f32x4 o[4];
        #pragma unroll
        for (int n = 0; n < 4; n++) o[n] = (f32x4){0.f, 0.f, 0.f, 0.f};
        f32x4 mrow = {-1e30f, -1e30f, -1e30f, -1e30f};
        f32x4 lrow = {0.f, 0.f, 0.f, 0.f};   // per-lane partial denominator

        int nch = (q0 >> 7) + 1;         // block-uniform (exact for all waves)

        // prefetch chunk 0 into registers
        short8 ka0, ka1, ka2, ka3, va0, va1, va2, va3;
        {
            const unsigned short* kp = Kb + (size_t)rowK * DHH + colK;
            ka0 = *(const short8*)kp;
            ka1 = *(const short8*)(kp + 8);
            ka2 = *(const short8*)(kp + 16);
            ka3 = *(const short8*)(kp + 24);
            const unsigned short* vp = Vb + (size_t)rowV * TLEN + colV;
            va0 = *(const short8*)vp;
            va1 = *(const short8*)(vp + 8);
            va2 = *(const short8*)(vp + 16);
            va3 = *(const short8*)(vp + 24);
        }

        for (int ch = 0; ch < nch; ch++) {
            int s0 = ch * 128;
            __syncthreads();             // all waves done reading prior chunk
            *(short8*)(&Ks[rowK * 72 + colK])       = ka0;
            *(short8*)(&Ks[rowK * 72 + colK + 8])   = ka1;
            *(short8*)(&Ks[rowK * 72 + colK + 16])  = ka2;
            *(short8*)(&Ks[rowK * 72 + colK + 24])  = ka3;
            *(short8*)(&Vs[rowV * 136 + colV])      = va0;
            *(short8*)(&Vs[rowV * 136 + colV + 8])  = va1;
            *(short8*)(&Vs[rowV * 136 + colV + 16]) = va2;
            *(short8*)(&Vs[rowV * 136 + colV + 24]) = va3;
            __syncthreads();             // staged

            if (ch + 1 < nch) {          // T14: next chunk's loads hide here
                int s1 = s0 + 128;
                const unsigned short* kp = Kb + (size_t)(s1 + rowK) * DHH + colK;
                ka0 = *(const short8*)kp;
                ka1 = *(const short8*)(kp + 8);
                ka2 = *(const short8*)(kp + 16);
                ka3 = *(const short8*)(kp + 24);
                const unsigned short* vp = Vb + (size_t)rowV * TLEN + s1 + colV;
                va0 = *(const short8*)vp;
                va1 = *(const short8*)(vp + 8);
                va2 = *(const short8*)(vp + 16);
                va3 = *(const short8*)(vp + 24);
            }

            // ---- QK^T: S[q 16][s 128] (already in exp2 domain via Q scale) --
            f32x4 S[8];
            #pragma unroll
            for (int n = 0; n < 8; n++) {
                short8 b0 = *(const short8*)(&Ks[(n * 16 + l16) * 72 + quad * 8]);
                short8 b1 = *(const short8*)(&Ks[(n * 16 + l16) * 72 + 32 + quad * 8]);
                f32x4 s = (f32x4){0.f, 0.f, 0.f, 0.f};
                s = __builtin_amdgcn_mfma_f32_16x16x32_bf16(aq0, b0, s, 0, 0, 0);
                s = __builtin_amdgcn_mfma_f32_16x16x32_bf16(aq1, b1, s, 0, 0, 0);
                S[n] = s;
            }
            bool needmask = (s0 + 127 > qw);  // wave-uniform; diag chunk(s)
            // ---- online softmax (exp2 domain) ----
            #pragma unroll
            for (int r = 0; r < 4; r++) {
                float xv[8];
                #pragma unroll
                for (int n = 0; n < 8; n++) {
                    float xx = S[n][r];
                    if (needmask && (s0 + n * 16 + l16 > qw + quad * 4 + r)) xx = -1e30f;
                    xv[n] = xx;
                }
                float mxl = fmaxf(fmaxf(fmaxf(xv[0], xv[1]), fmaxf(xv[2], xv[3])),
                                  fmaxf(fmaxf(xv[4], xv[5]), fmaxf(xv[6], xv[7])));
                float used;
                if (__all(mxl <= mrow[r] + 8.0f)) {       // defer-rescale (T13)
                    used = mrow[r];
                } else {
                    float mx = mxl;
                    mx = fmaxf(mx, __shfl_xor(mx, 1, 64));
                    mx = fmaxf(mx, __shfl_xor(mx, 2, 64));
                    mx = fmaxf(mx, __shfl_xor(mx, 4, 64));
                    mx = fmaxf(mx, __shfl_xor(mx, 8, 64));
                    float mnew  = fmaxf(mrow[r], mx);
                    float alpha = fexp2(mrow[r] - mnew);
                    lrow[r] *= alpha;
                    o[0][r] *= alpha; o[1][r] *= alpha;
                    o[2][r] *= alpha; o[3][r] *= alpha;
                    mrow[r] = mnew;
                    used = mnew;
                }
                float ps = 0.f;
                int prow = (quad * 4 + r) * 136;
                #pragma unroll
                for (int n = 0; n < 8; n++) {
                    float p = fexp2(xv[n] - used);
                    ps += p;
                    Pw[prow + n * 16 + l16] = f2bf_trunc(p);
                }
                lrow[r] += ps;
            }
            // ---- PV: O += P[16x128] * V[128x64] ----
            short8 ap[4];
            #pragma unroll
            for (int ks = 0; ks < 4; ks++)
                ap[ks] = *(const short8*)(Pw + l16 * 136 + ks * 32 + quad * 8);
            #pragma unroll
            for (int n = 0; n < 4; n++) {
                #pragma unroll
                for (int ks = 0; ks < 4; ks++) {
                    short8 b = *(const short8*)(&Vs[(n * 16 + l16) * 136 + ks * 32 + quad * 8]);
                    o[n] = __builtin_amdgcn_mfma_f32_16x16x32_bf16(ap[ks], b, o[n], 0, 0, 0);
                }
            }
        }

        // ---- output this tile ----
        #pragma unroll
        for (int r = 0; r < 4; r++) {
            float ls = lrow[r];
            ls += __shfl_xor(ls, 1, 64);
            ls += __shfl_xor(ls, 2, 64);
            ls += __shfl_xor(ls, 4, 64);
            ls += __shfl_xor(ls, 8, 64);
            float inv = 1.0f / ls;
            int t = qw + quad * 4 + r;
            size_t rowoff = ((size_t)(bidx * TLEN + t)) * EDIM + hh * 64;
            #pragma unroll
            for (int n = 0; n < 4; n++)
                att[rowoff + n * 16 + l16] = f2bf(o[n][r] * inv);
        }
    }
}

// ---------------- launcher ----------------
extern "C" void kernel_launch(void* const* d_in, const int* in_sizes, int n_in,
                              void* d_out, int out_size, void* d_ws, size_t ws_size,
                              hipStream_t stream)
{
    (void)in_sizes; (void)n_in; (void)out_size; (void)ws_size;
    const float* x   = (const float*)d_in[0];
    const float* Wq  = (const float*)d_in[1];
    const float* bq  = (const float*)d_in[2];
    const float* Wk  = (const float*)d_in[3];
    const float* bk  = (const float*)d_in[4];
    const float* Wv  = (const float*)d_in[5];
    const float* bv  = (const float*)d_in[6];
    const float* Wo  = (const float*)d_in[7];
    const float* bo  = (const float*)d_in[8];
    const float* W1  = (const float*)d_in[9];
    const float* b1  = (const float*)d_in[10];
    const float* W2  = (const float*)d_in[11];
    const float* b2  = (const float*)d_in[12];
    const float* g1  = (const float*)d_in[13];
    const float* be1 = (const float*)d_in[14];
    const float* g2  = (const float*)d_in[15];
    const float* be2 = (const float*)d_in[16];

    // ws layout (ushort elems; total byte use < proven 42,008,640):
    //   xn/vtg/xn2 bytes 0..8M | q 8..16M (later x1) | k 16..24M (later WoT/W1T
    //   16..20M, W2T 20..24M) | v 24..32M | WqT/WkT/WvT 32..38M (contiguous
    //   [3072][1024] for fused QKV) then att 32..40M | biasf @ elem 19922944
    //   (byte 39,845,888; live only during QKV, att overwrites later) |
    //   h 24..40M (over v+att)
    unsigned short* ws  = (unsigned short*)d_ws;
    unsigned short* xn  = ws;                  // 4096x1024 bf16 (xn, vtg, xn2)
    unsigned short* vtg = ws;                  // V^T [32][64][2048] over xn
    unsigned short* qb  = ws + 4194304;        // q|k|v contiguous slots
    unsigned short* kb  = ws + 8388608;
    unsigned short* vb  = ws + 12582912;
    unsigned short* wqt = ws + 16777216;       // [3072][1024] fused Bt
    unsigned short* att = ws + 16777216;       // 4096x1024 bf16 (over WT, dead)
    unsigned short* x1  = ws + 4194304;        // over q (dead after attn)
    unsigned short* wot = ws + 8388608;        // over k (dead after attn)
    unsigned short* w1t = ws + 8388608;        // 2048x1024 bf16 (over WoT, dead)
    unsigned short* w2t = ws + 10485760;       // 1024x2048 bf16
    unsigned short* hb  = ws + 12582912;       // 4096x2048 bf16 (over v+att, dead)
    float* biasf = (float*)(ws + 19922944);    // f32[3072] fused QKV bias

    dim3 gT64(16, 16);                 // 1024x1024 transpose
    dim3 gE64(EDIM / 64, BT / 64);     // (16,64) = 1024 blocks, BM=64 gemms
    dim3 gQKV(3072 / 128, BT / 128);   // (24,32) fused QKV BN=128
    dim3 gF(2048 / 128, BT / 128);     // (16,32) FF1 halves BN=128

    // weight transposes for phase 1 (wqt/wkt/wvt contiguous), one launch
    transpose_qkv3_kernel<<<dim3(16, 16, 3), 256, 0, stream>>>(Wq, Wk, Wv, wqt);
    bias_fuse_kernel<<<dim3(12), 256, 0, stream>>>(bq, bk, bv, biasf);

    // LN1 -> xn (fused stats+apply)
    ln_fused_kernel<1><<<BT, 256, 0, stream>>>(x, g1, be1, xn);

    // fused QKV: one gemm, N=3072, BN=128 (Q pre-scaled in epilogue)
    gemm_bt_kernel<V_QKV, 128><<<gQKV, 256, 0, stream>>>(xn, wqt, biasf, nullptr, qb, 3072, EDIM);

    // V^T once per head (xn dead from here until LN2 rewrites it)
    vtrans_kernel<<<dim3(NH * 2, TLEN / 64), 256, 0, stream>>>(vb, vtg);

    attn_kernel<<<dim3(512), 256, 0, stream>>>(qb, kb, vtg, att);

    // WO (+resid x f32) -> x1 bf16  (BM=64: 1024 blocks, 4/CU)
    transpose_kernel<0><<<gT64, 256, 0, stream>>>(Wo, wot, EDIM, EDIM);
    gemm_bt64_kernel<V_WO><<<gE64, 256, 0, stream>>>(att, wot, bo, x, x1, EDIM, EDIM);

    // LN2 -> xn2 (same slot as xn, fused stats+apply)
    ln_fused_kernel<0><<<BT, 256, 0, stream>>>(x1, g2, be2, xn);

    // FFN, split-K x2 to fit ws: h half = [4096][2048]
    // half A: W1[:, 0:2048], W2[0:2048, :]  (both transposes in one launch)
    transpose_ffn_kernel<<<dim3(32, 16, 2), 256, 0, stream>>>(W1, W2, w1t, w2t);
    gemm_bt_kernel<V_FF1, 128><<<gF, 256, 0, stream>>>(xn, w1t, b1, nullptr, hb, 2048, EDIM);
    gemm_bt64_kernel<V_FF2A><<<gE64, 256, 0, stream>>>(hb, w2t, nullptr, nullptr, d_out, EDIM, 2048);
    // half B: W1[:, 2048:4096], W2[2048:4096, :]
    transpose_ffn_kernel<<<dim3(32, 16, 2), 256, 0, stream>>>(W1 + 2048, W2 + (size_t)2048 * EDIM, w1t, w2t);
    gemm_bt_kernel<V_FF1, 128><<<gF, 256, 0, stream>>>(xn, w1t, b1 + 2048, nullptr, hb, 2048, EDIM);
    gemm_bt64_kernel<V_FF2B><<<gE64, 256, 0, stream>>>(hb, w2t, b2, x1, d_out, EDIM, 2048);
}

// Round 12
// 408.523 us; speedup vs baseline: 1.1880x; 1.0046x over previous
//
#include <hip/hip_runtime.h>
#include <stdint.h>

// ---------- problem constants ----------
// WORLD MODEL: external inputs and d_out are FLOAT32 (ref is jnp.float32).
// Internal activations/weights bf16 for MFMA. Threshold 0.125 covers bf16.
#define BT    4096   // B*T
#define EDIM  1024
#define TLEN  2048
#define NH    16
#define DHH   64
#define DFFN  4096

typedef short short8 __attribute__((ext_vector_type(8)));
typedef float f32x4  __attribute__((ext_vector_type(4)));

typedef const __attribute__((address_space(1))) unsigned int* gas_ptr;
typedef __attribute__((address_space(3))) unsigned int*       las_ptr;

__device__ __forceinline__ float bf2f(unsigned short u) {
    union { unsigned int i; float f; } c; c.i = ((unsigned int)u) << 16; return c.f;
}
__device__ __forceinline__ unsigned short f2bf(float f) {
    union { float f; unsigned int i; } c; c.f = f;
    unsigned int u = c.i;
    unsigned int r = u + 0x7fffu + ((u >> 16) & 1u);   // RNE
    return (unsigned short)(r >> 16);
}
__device__ __forceinline__ unsigned short f2bf_trunc(float f) {
    union { float f; unsigned int i; } c; c.f = f;    // truncate: P-only (cheap)
    return (unsigned short)(c.i >> 16);
}
__device__ __forceinline__ float fexp2(float x) {
#if __has_builtin(__builtin_amdgcn_exp2f)
    return __builtin_amdgcn_exp2f(x);
#else
    return __expf(x * 0.69314718056f);
#endif
}
// async global->LDS 16B: per-lane global src, wave-uniform LDS base + lane*16.
__device__ __forceinline__ void gload16(const unsigned short* g, unsigned short* l) {
    __builtin_amdgcn_global_load_lds((gas_ptr)g, (las_ptr)l, 16, 0, 0);
}

#define CS_SCALE 0.18033688011f   // 0.125 * log2(e), folded into Q at QKV epilogue

// ---------------- weight transpose: f32 [K][N] -> bf16 [N][K] ----------------
// grid: (Nout/64, Kdim/64), 256 threads, 64x64 f32 tile in LDS.
template<int QKV>
__global__ __launch_bounds__(256) void transpose_kernel(
    const float* src, unsigned short* dst, int Kdim, int srcStride)
{
    __shared__ float T[64][65];
    int t = threadIdx.x;
    int n0 = blockIdx.x * 64, k0 = blockIdx.y * 64;
    int r = t >> 4, c4 = (t & 15) * 4;
    #pragma unroll
    for (int i = 0; i < 4; i++) {
        int rr = r + i * 16;
        const float* p;
        if (QKV) p = src + ((size_t)(n0 >> 6)) * 65536 + (size_t)(k0 + rr) * 64 + c4;
        else     p = src + (size_t)(k0 + rr) * srcStride + n0 + c4;
        float4 v = *(const float4*)p;
        T[c4 + 0][rr] = v.x;
        T[c4 + 1][rr] = v.y;
        T[c4 + 2][rr] = v.z;
        T[c4 + 3][rr] = v.w;
    }
    __syncthreads();
    int rn = t >> 2, ck = (t & 3) * 16;
    short8 o0, o1;
    #pragma unroll
    for (int j = 0; j < 8; j++) o0[j] = (short)f2bf(T[rn][ck + j]);
    #pragma unroll
    for (int j = 0; j < 8; j++) o1[j] = (short)f2bf(T[rn][ck + 8 + j]);
    unsigned short* dp = dst + (size_t)(n0 + rn) * Kdim + k0 + ck;
    *(short8*)dp       = o0;
    *(short8*)(dp + 8) = o1;
}

// ---------------- combined Wq/Wk/Wv transpose (grid.z = 3) -------------------
__global__ __launch_bounds__(256) void transpose_qkv3_kernel(
    const float* __restrict__ Wq, const float* __restrict__ Wk,
    const float* __restrict__ Wv, unsigned short* __restrict__ dstbase)
{
    __shared__ float T[64][65];
    int z = blockIdx.z;
    const float* src = (z == 0) ? Wq : (z == 1) ? Wk : Wv;
    unsigned short* dst = dstbase + (size_t)z * 1048576;
    int t = threadIdx.x;
    int n0 = blockIdx.x * 64, k0 = blockIdx.y * 64;
    int r = t >> 4, c4 = (t & 15) * 4;
    #pragma unroll
    for (int i = 0; i < 4; i++) {
        int rr = r + i * 16;
        const float* p = src + ((size_t)(n0 >> 6)) * 65536 + (size_t)(k0 + rr) * 64 + c4;
        float4 v = *(const float4*)p;
        T[c4 + 0][rr] = v.x;
        T[c4 + 1][rr] = v.y;
        T[c4 + 2][rr] = v.z;
        T[c4 + 3][rr] = v.w;
    }
    __syncthreads();
    int rn = t >> 2, ck = (t & 3) * 16;
    short8 o0, o1;
    #pragma unroll
    for (int j = 0; j < 8; j++) o0[j] = (short)f2bf(T[rn][ck + j]);
    #pragma unroll
    for (int j = 0; j < 8; j++) o1[j] = (short)f2bf(T[rn][ck + 8 + j]);
    unsigned short* dp = dst + (size_t)(n0 + rn) * EDIM + k0 + ck;
    *(short8*)dp       = o0;
    *(short8*)(dp + 8) = o1;
}

// ------------- combined FFN-half transpose: W1 slice + W2 slice (z=2) --------
__global__ __launch_bounds__(256) void transpose_ffn_kernel(
    const float* __restrict__ W1h, const float* __restrict__ W2h,
    unsigned short* __restrict__ w1t, unsigned short* __restrict__ w2t)
{
    __shared__ float T[64][65];
    int z = blockIdx.z;
    const float* src;
    unsigned short* dst;
    int Kdim, sstride, n0, k0;
    if (z == 0) { src = W1h; dst = w1t; Kdim = 1024; sstride = 4096;
                  n0 = blockIdx.x * 64; k0 = blockIdx.y * 64; }
    else        { src = W2h; dst = w2t; Kdim = 2048; sstride = 1024;
                  n0 = blockIdx.y * 64; k0 = blockIdx.x * 64; }
    int t = threadIdx.x;
    int r = t >> 4, c4 = (t & 15) * 4;
    #pragma unroll
    for (int i = 0; i < 4; i++) {
        int rr = r + i * 16;
        const float* p = src + (size_t)(k0 + rr) * sstride + n0 + c4;
        float4 v = *(const float4*)p;
        T[c4 + 0][rr] = v.x;
        T[c4 + 1][rr] = v.y;
        T[c4 + 2][rr] = v.z;
        T[c4 + 3][rr] = v.w;
    }
    __syncthreads();
    int rn = t >> 2, ck = (t & 3) * 16;
    short8 o0, o1;
    #pragma unroll
    for (int j = 0; j < 8; j++) o0[j] = (short)f2bf(T[rn][ck + j]);
    #pragma unroll
    for (int j = 0; j < 8; j++) o1[j] = (short)f2bf(T[rn][ck + 8 + j]);
    unsigned short* dp = dst + (size_t)(n0 + rn) * Kdim + k0 + ck;
    *(short8*)dp       = o0;
    *(short8*)(dp + 8) = o1;
}

// ---------------- V transpose: bf16 [bh][2048][64] -> bf16 [bh][64][2048] ----
__global__ __launch_bounds__(256) void vtrans_kernel(
    const unsigned short* __restrict__ v, unsigned short* __restrict__ vt)
{
    __shared__ __align__(16) unsigned short T[64][72];
    int bh = blockIdx.x, st = blockIdx.y;
    int t = threadIdx.x;
    int r = t >> 2, c = (t & 3) * 16;
    const unsigned short* src = v + ((size_t)bh * TLEN + st * 64) * DHH;
    short8 a0 = *(const short8*)(src + r * DHH + c);
    short8 a1 = *(const short8*)(src + r * DHH + c + 8);
    *(short8*)&T[r][c]     = a0;
    *(short8*)&T[r][c + 8] = a1;
    __syncthreads();
    int d = t >> 2;
    short8 o0, o1;
    #pragma unroll
    for (int j = 0; j < 8; j++) o0[j] = (short)T[c + j][d];
    #pragma unroll
    for (int j = 0; j < 8; j++) o1[j] = (short)T[c + 8 + j][d];
    unsigned short* dst = vt + ((size_t)bh * DHH + d) * TLEN + st * 64 + c;
    *(short8*)dst       = o0;
    *(short8*)(dst + 8) = o1;
}

// ---------------- fused QKV bias: [bq|bk|bv] -> f32[3072] ----------------
__global__ __launch_bounds__(256) void bias_fuse_kernel(
    const float* __restrict__ bq, const float* __restrict__ bk,
    const float* __restrict__ bv, float* __restrict__ dst)
{
    int t = blockIdx.x * 256 + threadIdx.x;           // grid 12 -> 3072
    const float* src = (t < 1024) ? bq : (t < 2048) ? bk : bv;
    dst[t] = src[t & 1023];
}

// ---------------- fused LN (stats + apply in one pass) -----------------------
template<int F32IN>
__global__ __launch_bounds__(256) void ln_fused_kernel(
    const void* __restrict__ x, const float* __restrict__ g,
    const float* __restrict__ b, unsigned short* __restrict__ out)
{
    int row = blockIdx.x, tid = threadIdx.x;
    size_t off = (size_t)row * EDIM + tid * 4;
    float v0, v1, v2, v3;
    if (F32IN) {
        float4 a = *(const float4*)((const float*)x + off);
        v0 = a.x; v1 = a.y; v2 = a.z; v3 = a.w;
    } else {
        ushort4 raw = *(const ushort4*)((const unsigned short*)x + off);
        v0 = bf2f(raw.x); v1 = bf2f(raw.y); v2 = bf2f(raw.z); v3 = bf2f(raw.w);
    }
    float s  = v0 + v1 + v2 + v3;
    float ss = v0*v0 + v1*v1 + v2*v2 + v3*v3;
    #pragma unroll
    for (int o = 1; o < 64; o <<= 1) {
        s  += __shfl_xor(s,  o, 64);
        ss += __shfl_xor(ss, o, 64);
    }
    __shared__ float red[8];
    int wave = tid >> 6;
    if ((tid & 63) == 0) { red[wave*2] = s; red[wave*2+1] = ss; }
    __syncthreads();
    s  = red[0] + red[2] + red[4] + red[6];
    ss = red[1] + red[3] + red[5] + red[7];
    float m  = s * (1.0f / EDIM);
    float rs = rsqrtf(ss * (1.0f / EDIM) - m * m + 1e-5f);
    float4 gv = *(const float4*)(g + tid * 4);
    float4 bv = *(const float4*)(b + tid * 4);
    ushort4 o;
    o.x = f2bf((v0 - m) * rs * gv.x + bv.x);
    o.y = f2bf((v1 - m) * rs * gv.y + bv.y);
    o.z = f2bf((v2 - m) * rs * gv.z + bv.z);
    o.w = f2bf((v3 - m) * rs * gv.w + bv.w);
    *(ushort4*)(out + off) = o;
}

// ------------- gemm_bt64: BM=64, BN template (64/128), all variants ----------
// R10 proved BM=64 (more blocks/CU -> wave-level overlap of the barrier drain,
// m114 mechanism) on WO/FF2A/FF2B. R11 extends it to QKV (grid 1536 = 6/CU)
// and FF1 (1024 = 4/CU). LDS 16-24KB, acc 2xNJ frags. m97 staging structure.
#define V_QKV  0
#define V_WO   1
#define V_FF1  2
#define V_FF2A 3
#define V_FF2B 4

template<int VARIANT, int BN>
__global__ __launch_bounds__(256) void gemm_bt64_kernel(
    const unsigned short* A,        // bf16 [M][K]
    const unsigned short* Bt,       // bf16 [N][K]
    const float* bias,              // f32 (not read for FF2A)
    const void* resid,              // WO: f32 x ; FF2B: bf16 x1
    void* out,                      // QKV/FF1/WO: bf16 ; FF2A/B: f32 d_out
    int N, int K)
{
    constexpr int NJ = BN / 32;     // B frags per wave; also B gload issues
    __shared__ __align__(16) unsigned short As[64 * 64];
    __shared__ __align__(16) unsigned short Bs[BN * 64];
    int tid  = threadIdx.x;
    int lane = tid & 63, wave = tid >> 6;
    int quad = lane >> 4, l16 = lane & 15;
    int wr = wave >> 1, wc = wave & 1;        // 2x2 waves
    int m0 = blockIdx.y * 64, n0 = blockIdx.x * BN;

    f32x4 acc[2][NJ];
    #pragma unroll
    for (int i = 0; i < 2; i++)
        #pragma unroll
        for (int j = 0; j < NJ; j++) acc[i][j] = (f32x4){0.f, 0.f, 0.f, 0.f};

    int lr = lane >> 3;            // row within 8-row stripe
    int lc = (lane & 7) * 8;       // col elems (16B units)

    for (int k0 = 0; k0 < K; k0 += 64) {
        #pragma unroll
        for (int i = 0; i < 2; i++) {
            int blk = i * 4 + wave;            // 8 stripes cover 64 rows
            gload16(A + (size_t)(m0 + blk * 8 + lr) * K + k0 + lc, &As[blk * 512]);
        }
        #pragma unroll
        for (int i = 0; i < NJ; i++) {
            int blk = i * 4 + wave;            // BN/8 stripes cover BN rows
            gload16(Bt + (size_t)(n0 + blk * 8 + lr) * K + k0 + lc, &Bs[blk * 512]);
        }
        __syncthreads();           // vmcnt(0) drain: tile ready

        #pragma unroll
        for (int ks = 0; ks < 2; ks++) {
            short8 af[2], bf[NJ];
            #pragma unroll
            for (int i = 0; i < 2; i++)
                af[i] = *(const short8*)(&As[(wr * 32 + i * 16 + l16) * 64 + ks * 32 + quad * 8]);
            #pragma unroll
            for (int j = 0; j < NJ; j++)
                bf[j] = *(const short8*)(&Bs[(wc * (BN / 2) + j * 16 + l16) * 64 + ks * 32 + quad * 8]);
            #pragma unroll
            for (int i = 0; i < 2; i++)
                #pragma unroll
                for (int j = 0; j < NJ; j++)
                    acc[i][j] = __builtin_amdgcn_mfma_f32_16x16x32_bf16(af[i], bf[j], acc[i][j], 0, 0, 0);
        }

        __syncthreads();           // readers done before next stage overwrites
    }

    // epilogue: row = m0+wr*32+i*16+quad*4+r ; col = n0+wc*(BN/2)+j*16+l16
    #pragma unroll
    for (int j = 0; j < NJ; j++) {
        int c = n0 + wc * (BN / 2) + j * 16 + l16;
        float bi = (VARIANT == V_FF2A) ? 0.0f : bias[c];
        #pragma unroll
        for (int i = 0; i < 2; i++) {
            #pragma unroll
            for (int r = 0; r < 4; r++) {
                int m = m0 + wr * 32 + i * 16 + quad * 4 + r;
                float val = acc[i][j][r] + bi;
                if (VARIANT == V_QKV) {
                    int b = m >> 11, t = m & 2047;
                    int mat = c >> 10, cc = c & 1023;
                    int h = cc >> 6, d = cc & 63;
                    if (mat == 0) val *= CS_SCALE;   // fold softmax scale into Q
                    ((unsigned short*)out)[(size_t)mat * 4194304 +
                        (((size_t)(b * NH + h)) * TLEN + t) * DHH + d] = f2bf(val);
                } else if (VARIANT == V_FF1) {
                    val = fmaxf(val, 0.0f);
                    ((unsigned short*)out)[(size_t)m * N + c] = f2bf(val);
                } else if (VARIANT == V_WO) {
                    val += ((const float*)resid)[(size_t)m * N + c];
                    ((unsigned short*)out)[(size_t)m * N + c] = f2bf(val);
                } else if (VARIANT == V_FF2A) {
                    ((float*)out)[(size_t)m * N + c] = val;
                } else {  // V_FF2B
                    val += bf2f(((const unsigned short*)resid)[(size_t)m * N + c])
                         + ((const float*)out)[(size_t)m * N + c];
                    ((float*)out)[(size_t)m * N + c] = val;
                }
            }
        }
    }
}

// ---------------- flash attention v7.1: balanced pairing + pre-scaled Q ------
// R9 proven structure (63us). Q arrives pre-scaled by 0.125*log2e.
__global__ __launch_bounds__(256) void attn_kernel(
    const unsigned short* __restrict__ q,
    const unsigned short* __restrict__ k,
    const unsigned short* __restrict__ vt,   // [bh][64 d][2048 s]
    unsigned short* __restrict__ att)
{
    __shared__ __align__(16) unsigned short Ks[128 * 72];     // 18.0 KB
    __shared__ __align__(16) unsigned short Vs[64 * 136];     // 17.0 KB
    __shared__ __align__(16) unsigned short Ps[4][16 * 136];  // 17.0 KB
    int tid  = threadIdx.x;
    int lane = tid & 63, wave = tid >> 6;
    int quad = lane >> 4, l16 = lane & 15;

    int flat = blockIdx.x;               // 0..511
    int xcd  = flat & 7, idx = flat >> 3;
    int bh   = xcd * 4 + (idx >> 4);     // 4 heads per XCD
    int pp   = idx & 15;                 // pair index: tiles pp and 31-pp

    const unsigned short* Kb = k  + (size_t)bh * TLEN * DHH;
    const unsigned short* Vb = vt + (size_t)bh * DHH * TLEN;
    unsigned short* Pw = Ps[wave];

    int rowK = tid >> 1, colK = (tid & 1) * 32;
    int rowV = tid >> 2, colV = (tid & 3) * 32;
    int bidx = bh >> 4, hh = bh & 15;

    for (int half = 0; half < 2; ++half) {
        int qt = half ? (31 - pp) : pp;
        int q0 = qt * 64;
        int qw = q0 + wave * 16;         // this wave's 16 q-rows

        const unsigned short* Qb = q + ((size_t)bh * TLEN + qw) * DHH;
        short8 aq0 = *(const short8*)(Qb + l16 * DHH + quad * 8);
        short8 aq1 = *(const short8*)(Qb + l16 * DHH + 32 + quad * 8);

        f32x4 o[4];
        #pragma unroll
        for (int n = 0; n < 4; n++) o[n] = (f32x4){0.f, 0.f, 0.f, 0.f};
        f32x4 mrow = {-1e30f, -1e30f, -1e30f, -1e30f};
        f32x4 lrow = {0.f, 0.f, 0.f, 0.f};   // per-lane partial denominator

        int nch = (q0 >> 7) + 1;         // block-uniform (exact for all waves)

        // prefetch chunk 0 into registers
        short8 ka0, ka1, ka2, ka3, va0, va1, va2, va3;
        {
            const unsigned short* kp = Kb + (size_t)rowK * DHH + colK;
            ka0 = *(const short8*)kp;
            ka1 = *(const short8*)(kp + 8);
            ka2 = *(const short8*)(kp + 16);
            ka3 = *(const short8*)(kp + 24);
            const unsigned short* vp = Vb + (size_t)rowV * TLEN + colV;
            va0 = *(const short8*)vp;
            va1 = *(const short8*)(vp + 8);
            va2 = *(const short8*)(vp + 16);
            va3 = *(const short8*)(vp + 24);
        }

        for (int ch = 0; ch < nch; ch++) {
            int s0 = ch * 128;
            __syncthreads();             // all waves done reading prior chunk
            *(short8*)(&Ks[rowK * 72 + colK])       = ka0;
            *(short8*)(&Ks[rowK * 72 + colK + 8])   = ka1;
            *(short8*)(&Ks[rowK * 72 + colK + 16])  = ka2;
            *(short8*)(&Ks[rowK * 72 + colK + 24])  = ka3;
            *(short8*)(&Vs[rowV * 136 + colV])      = va0;
            *(short8*)(&Vs[rowV * 136 + colV + 8])  = va1;
            *(short8*)(&Vs[rowV * 136 + colV + 16]) = va2;
            *(short8*)(&Vs[rowV * 136 + colV + 24]) = va3;
            __syncthreads();             // staged

            if (ch + 1 < nch) {          // T14: next chunk's loads hide here
                int s1 = s0 + 128;
                const unsigned short* kp = Kb + (size_t)(s1 + rowK) * DHH + colK;
                ka0 = *(const short8*)kp;
                ka1 = *(const short8*)(kp + 8);
                ka2 = *(const short8*)(kp + 16);
                ka3 = *(const short8*)(kp + 24);
                const unsigned short* vp = Vb + (size_t)rowV * TLEN + s1 + colV;
                va0 = *(const short8*)vp;
                va1 = *(const short8*)(vp + 8);
                va2 = *(const short8*)(vp + 16);
                va3 = *(const short8*)(vp + 24);
            }

            // ---- QK^T: S[q 16][s 128] (exp2 domain via pre-scaled Q) ----
            f32x4 S[8];
            #pragma unroll
            for (int n = 0; n < 8; n++) {
                short8 b0 = *(const short8*)(&Ks[(n * 16 + l16) * 72 + quad * 8]);
                short8 b1 = *(const short8*)(&Ks[(n * 16 + l16) * 72 + 32 + quad * 8]);
                f32x4 s = (f32x4){0.f, 0.f, 0.f, 0.f};
                s = __builtin_amdgcn_mfma_f32_16x16x32_bf16(aq0, b0, s, 0, 0, 0);
                s = __builtin_amdgcn_mfma_f32_16x16x32_bf16(aq1, b1, s, 0, 0, 0);
                S[n] = s;
            }
            bool needmask = (s0 + 127 > qw);  // wave-uniform; diag chunk(s)
            // ---- online softmax (exp2 domain) ----
            #pragma unroll
            for (int r = 0; r < 4; r++) {
                float xv[8];
                #pragma unroll
                for (int n = 0; n < 8; n++) {
                    float xx = S[n][r];
                    if (needmask && (s0 + n * 16 + l16 > qw + quad * 4 + r)) xx = -1e30f;
                    xv[n] = xx;
                }
                float mxl = fmaxf(fmaxf(fmaxf(xv[0], xv[1]), fmaxf(xv[2], xv[3])),
                                  fmaxf(fmaxf(xv[4], xv[5]), fmaxf(xv[6], xv[7])));
                float used;
                if (__all(mxl <= mrow[r] + 8.0f)) {       // defer-rescale (T13)
                    used = mrow[r];
                } else {
                    float mx = mxl;
                    mx = fmaxf(mx, __shfl_xor(mx, 1, 64));
                    mx = fmaxf(mx, __shfl_xor(mx, 2, 64));
                    mx = fmaxf(mx, __shfl_xor(mx, 4, 64));
                    mx = fmaxf(mx, __shfl_xor(mx, 8, 64));
                    float mnew  = fmaxf(mrow[r], mx);
                    float alpha = fexp2(mrow[r] - mnew);
                    lrow[r] *= alpha;
                    o[0][r] *= alpha; o[1][r] *= alpha;
                    o[2][r] *= alpha; o[3][r] *= alpha;
                    mrow[r] = mnew;
                    used = mnew;
                }
                float ps = 0.f;
                int prow = (quad * 4 + r) * 136;
                #pragma unroll
                for (int n = 0; n < 8; n++) {
                    float p = fexp2(xv[n] - used);
                    ps += p;
                    Pw[prow + n * 16 + l16] = f2bf_trunc(p);
                }
                lrow[r] += ps;
            }
            // ---- PV: O += P[16x128] * V[128x64] ----
            short8 ap[4];
            #pragma unroll
            for (int ks = 0; ks < 4; ks++)
                ap[ks] = *(const short8*)(Pw + l16 * 136 + ks * 32 + quad * 8);
            #pragma unroll
            for (int n = 0; n < 4; n++) {
                #pragma unroll
                for (int ks = 0; ks < 4; ks++) {
                    short8 b = *(const short8*)(&Vs[(n * 16 + l16) * 136 + ks * 32 + quad * 8]);
                    o[n] = __builtin_amdgcn_mfma_f32_16x16x32_bf16(ap[ks], b, o[n], 0, 0, 0);
                }
            }
        }

        // ---- output this tile ----
        #pragma unroll
        for (int r = 0; r < 4; r++) {
            float ls = lrow[r];
            ls += __shfl_xor(ls, 1, 64);
            ls += __shfl_xor(ls, 2, 64);
            ls += __shfl_xor(ls, 4, 64);
            ls += __shfl_xor(ls, 8, 64);
            float inv = 1.0f / ls;
            int t = qw + quad * 4 + r;
            size_t rowoff = ((size_t)(bidx * TLEN + t)) * EDIM + hh * 64;
            #pragma unroll
            for (int n = 0; n < 4; n++)
                att[rowoff + n * 16 + l16] = f2bf(o[n][r] * inv);
        }
    }
}

// ---------------- launcher ----------------
extern "C" void kernel_launch(void* const* d_in, const int* in_sizes, int n_in,
                              void* d_out, int out_size, void* d_ws, size_t ws_size,
                              hipStream_t stream)
{
    (void)in_sizes; (void)n_in; (void)out_size; (void)ws_size;
    const float* x   = (const float*)d_in[0];
    const float* Wq  = (const float*)d_in[1];
    const float* bq  = (const float*)d_in[2];
    const float* Wk  = (const float*)d_in[3];
    const float* bk  = (const float*)d_in[4];
    const float* Wv  = (const float*)d_in[5];
    const float* bv  = (const float*)d_in[6];
    const float* Wo  = (const float*)d_in[7];
    const float* bo  = (const float*)d_in[8];
    const float* W1  = (const float*)d_in[9];
    const float* b1  = (const float*)d_in[10];
    const float* W2  = (const float*)d_in[11];
    const float* b2  = (const float*)d_in[12];
    const float* g1  = (const float*)d_in[13];
    const float* be1 = (const float*)d_in[14];
    const float* g2  = (const float*)d_in[15];
    const float* be2 = (const float*)d_in[16];

    // ws layout (ushort elems; total byte use < proven 42,008,640):
    //   xn/vtg/xn2 bytes 0..8M | q 8..16M (later x1) | k 16..24M (later WoT/W1T
    //   16..20M, W2T 20..24M) | v 24..32M | WqT/WkT/WvT 32..38M (contiguous
    //   [3072][1024] for fused QKV) then att 32..40M | biasf @ elem 19922944
    //   (byte 39,845,888; live only during QKV, att overwrites later) |
    //   h 24..40M (over v+att)
    unsigned short* ws  = (unsigned short*)d_ws;
    unsigned short* xn  = ws;                  // 4096x1024 bf16 (xn, vtg, xn2)
    unsigned short* vtg = ws;                  // V^T [32][64][2048] over xn
    unsigned short* qb  = ws + 4194304;        // q|k|v contiguous slots
    unsigned short* kb  = ws + 8388608;
    unsigned short* vb  = ws + 12582912;
    unsigned short* wqt = ws + 16777216;       // [3072][1024] fused Bt
    unsigned short* att = ws + 16777216;       // 4096x1024 bf16 (over WT, dead)
    unsigned short* x1  = ws + 4194304;        // over q (dead after attn)
    unsigned short* wot = ws + 8388608;        // over k (dead after attn)
    unsigned short* w1t = ws + 8388608;        // 2048x1024 bf16 (over WoT, dead)
    unsigned short* w2t = ws + 10485760;       // 1024x2048 bf16
    unsigned short* hb  = ws + 12582912;       // 4096x2048 bf16 (over v+att, dead)
    float* biasf = (float*)(ws + 19922944);    // f32[3072] fused QKV bias

    dim3 gT64(16, 16);                 // 1024x1024 transpose
    dim3 gE64(EDIM / 64, BT / 64);     // (16,64) = 1024 blocks, N=1024 gemms
    dim3 gQKV(3072 / 128, BT / 64);    // (24,64) = 1536 blocks, QKV BN=128
    dim3 gF(2048 / 128, BT / 64);      // (16,64) = 1024 blocks, FF1 BN=128

    // weight transposes for phase 1 (wqt/wkt/wvt contiguous), one launch
    transpose_qkv3_kernel<<<dim3(16, 16, 3), 256, 0, stream>>>(Wq, Wk, Wv, wqt);
    bias_fuse_kernel<<<dim3(12), 256, 0, stream>>>(bq, bk, bv, biasf);

    // LN1 -> xn (fused stats+apply)
    ln_fused_kernel<1><<<BT, 256, 0, stream>>>(x, g1, be1, xn);

    // fused QKV: one gemm, N=3072, BM=64/BN=128 (1536 blocks, 6/CU)
    gemm_bt64_kernel<V_QKV, 128><<<gQKV, 256, 0, stream>>>(xn, wqt, biasf, nullptr, qb, 3072, EDIM);

    // V^T once per head (xn dead from here until LN2 rewrites it)
    vtrans_kernel<<<dim3(NH * 2, TLEN / 64), 256, 0, stream>>>(vb, vtg);

    attn_kernel<<<dim3(512), 256, 0, stream>>>(qb, kb, vtg, att);

    // WO (+resid x f32) -> x1 bf16  (BM=64: 1024 blocks, 4/CU)
    transpose_kernel<0><<<gT64, 256, 0, stream>>>(Wo, wot, EDIM, EDIM);
    gemm_bt64_kernel<V_WO, 64><<<gE64, 256, 0, stream>>>(att, wot, bo, x, x1, EDIM, EDIM);

    // LN2 -> xn2 (same slot as xn, fused stats+apply)
    ln_fused_kernel<0><<<BT, 256, 0, stream>>>(x1, g2, be2, xn);

    // FFN, split-K x2 to fit ws: h half = [4096][2048]
    // half A: W1[:, 0:2048], W2[0:2048, :]  (both transposes in one launch)
    transpose_ffn_kernel<<<dim3(32, 16, 2), 256, 0, stream>>>(W1, W2, w1t, w2t);
    gemm_bt64_kernel<V_FF1, 128><<<gF, 256, 0, stream>>>(xn, w1t, b1, nullptr, hb, 2048, EDIM);
    gemm_bt64_kernel<V_FF2A, 64><<<gE64, 256, 0, stream>>>(hb, w2t, nullptr, nullptr, d_out, EDIM, 2048);
    // half B: W1[:, 2048:4096], W2[2048:4096, :]
    transpose_ffn_kernel<<<dim3(32, 16, 2), 256, 0, stream>>>(W1 + 2048, W2 + (size_t)2048 * EDIM, w1t, w2t);
    gemm_bt64_kernel<V_FF1, 128><<<gF, 256, 0, stream>>>(xn, w1t, b1 + 2048, nullptr, hb, 2048, EDIM);
    gemm_bt64_kernel<V_FF2B, 64><<<gE64, 256, 0, stream>>>(hb, w2t, b2, x1, d_out, EDIM, 2048);
}

// Round 13
// 398.388 us; speedup vs baseline: 1.2182x; 1.0254x over previous
//
#include <hip/hip_runtime.h>
#include <stdint.h>

// ---------- problem constants ----------
// WORLD MODEL: external inputs and d_out are FLOAT32 (ref is jnp.float32).
// Internal activations/weights bf16 for MFMA. Threshold 0.125 covers bf16.
#define BT    4096   // B*T
#define EDIM  1024
#define TLEN  2048
#define NH    16
#define DHH   64
#define DFFN  4096

typedef short short8 __attribute__((ext_vector_type(8)));
typedef float f32x4  __attribute__((ext_vector_type(4)));

typedef const __attribute__((address_space(1))) unsigned int* gas_ptr;
typedef __attribute__((address_space(3))) unsigned int*       las_ptr;

__device__ __forceinline__ float bf2f(unsigned short u) {
    union { unsigned int i; float f; } c; c.i = ((unsigned int)u) << 16; return c.f;
}
__device__ __forceinline__ unsigned short f2bf(float f) {
    union { float f; unsigned int i; } c; c.f = f;
    unsigned int u = c.i;
    unsigned int r = u + 0x7fffu + ((u >> 16) & 1u);   // RNE
    return (unsigned short)(r >> 16);
}
__device__ __forceinline__ float fexp2(float x) {
#if __has_builtin(__builtin_amdgcn_exp2f)
    return __builtin_amdgcn_exp2f(x);
#else
    return __expf(x * 0.69314718056f);
#endif
}
// pack two f32 into one u32 of 2 truncated bf16 (lo = a, hi = b)
__device__ __forceinline__ unsigned int pack_bf2(float a, float b) {
    union { float f; unsigned int i; } ca, cb; ca.f = a; cb.f = b;
    return (cb.i & 0xFFFF0000u) | (ca.i >> 16);
}
// async global->LDS 16B: per-lane global src, wave-uniform LDS base + lane*16.
__device__ __forceinline__ void gload16(const unsigned short* g, unsigned short* l) {
    __builtin_amdgcn_global_load_lds((gas_ptr)g, (las_ptr)l, 16, 0, 0);
}

#define CS_SCALE 0.18033688011f   // 0.125 * log2(e), folded into Q at QKV epilogue

// ---------------- weight transpose: f32 [K][N] -> bf16 [N][K] ----------------
// grid: (Nout/64, Kdim/64), 256 threads, 64x64 f32 tile in LDS.
template<int QKV>
__global__ __launch_bounds__(256) void transpose_kernel(
    const float* src, unsigned short* dst, int Kdim, int srcStride)
{
    __shared__ float T[64][65];
    int t = threadIdx.x;
    int n0 = blockIdx.x * 64, k0 = blockIdx.y * 64;
    int r = t >> 4, c4 = (t & 15) * 4;
    #pragma unroll
    for (int i = 0; i < 4; i++) {
        int rr = r + i * 16;
        const float* p;
        if (QKV) p = src + ((size_t)(n0 >> 6)) * 65536 + (size_t)(k0 + rr) * 64 + c4;
        else     p = src + (size_t)(k0 + rr) * srcStride + n0 + c4;
        float4 v = *(const float4*)p;
        T[c4 + 0][rr] = v.x;
        T[c4 + 1][rr] = v.y;
        T[c4 + 2][rr] = v.z;
        T[c4 + 3][rr] = v.w;
    }
    __syncthreads();
    int rn = t >> 2, ck = (t & 3) * 16;
    short8 o0, o1;
    #pragma unroll
    for (int j = 0; j < 8; j++) o0[j] = (short)f2bf(T[rn][ck + j]);
    #pragma unroll
    for (int j = 0; j < 8; j++) o1[j] = (short)f2bf(T[rn][ck + 8 + j]);
    unsigned short* dp = dst + (size_t)(n0 + rn) * Kdim + k0 + ck;
    *(short8*)dp       = o0;
    *(short8*)(dp + 8) = o1;
}

// ---------------- combined Wq/Wk/Wv transpose (grid.z = 3) -------------------
__global__ __launch_bounds__(256) void transpose_qkv3_kernel(
    const float* __restrict__ Wq, const float* __restrict__ Wk,
    const float* __restrict__ Wv, unsigned short* __restrict__ dstbase)
{
    __shared__ float T[64][65];
    int z = blockIdx.z;
    const float* src = (z == 0) ? Wq : (z == 1) ? Wk : Wv;
    unsigned short* dst = dstbase + (size_t)z * 1048576;
    int t = threadIdx.x;
    int n0 = blockIdx.x * 64, k0 = blockIdx.y * 64;
    int r = t >> 4, c4 = (t & 15) * 4;
    #pragma unroll
    for (int i = 0; i < 4; i++) {
        int rr = r + i * 16;
        const float* p = src + ((size_t)(n0 >> 6)) * 65536 + (size_t)(k0 + rr) * 64 + c4;
        float4 v = *(const float4*)p;
        T[c4 + 0][rr] = v.x;
        T[c4 + 1][rr] = v.y;
        T[c4 + 2][rr] = v.z;
        T[c4 + 3][rr] = v.w;
    }
    __syncthreads();
    int rn = t >> 2, ck = (t & 3) * 16;
    short8 o0, o1;
    #pragma unroll
    for (int j = 0; j < 8; j++) o0[j] = (short)f2bf(T[rn][ck + j]);
    #pragma unroll
    for (int j = 0; j < 8; j++) o1[j] = (short)f2bf(T[rn][ck + 8 + j]);
    unsigned short* dp = dst + (size_t)(n0 + rn) * EDIM + k0 + ck;
    *(short8*)dp       = o0;
    *(short8*)(dp + 8) = o1;
}

// ------------- combined FFN-half transpose: W1 slice + W2 slice (z=2) --------
__global__ __launch_bounds__(256) void transpose_ffn_kernel(
    const float* __restrict__ W1h, const float* __restrict__ W2h,
    unsigned short* __restrict__ w1t, unsigned short* __restrict__ w2t)
{
    __shared__ float T[64][65];
    int z = blockIdx.z;
    const float* src;
    unsigned short* dst;
    int Kdim, sstride, n0, k0;
    if (z == 0) { src = W1h; dst = w1t; Kdim = 1024; sstride = 4096;
                  n0 = blockIdx.x * 64; k0 = blockIdx.y * 64; }
    else        { src = W2h; dst = w2t; Kdim = 2048; sstride = 1024;
                  n0 = blockIdx.y * 64; k0 = blockIdx.x * 64; }
    int t = threadIdx.x;
    int r = t >> 4, c4 = (t & 15) * 4;
    #pragma unroll
    for (int i = 0; i < 4; i++) {
        int rr = r + i * 16;
        const float* p = src + (size_t)(k0 + rr) * sstride + n0 + c4;
        float4 v = *(const float4*)p;
        T[c4 + 0][rr] = v.x;
        T[c4 + 1][rr] = v.y;
        T[c4 + 2][rr] = v.z;
        T[c4 + 3][rr] = v.w;
    }
    __syncthreads();
    int rn = t >> 2, ck = (t & 3) * 16;
    short8 o0, o1;
    #pragma unroll
    for (int j = 0; j < 8; j++) o0[j] = (short)f2bf(T[rn][ck + j]);
    #pragma unroll
    for (int j = 0; j < 8; j++) o1[j] = (short)f2bf(T[rn][ck + 8 + j]);
    unsigned short* dp = dst + (size_t)(n0 + rn) * Kdim + k0 + ck;
    *(short8*)dp       = o0;
    *(short8*)(dp + 8) = o1;
}

// ---------------- V transpose: bf16 [bh][2048][64] -> bf16 [bh][64][2048] ----
__global__ __launch_bounds__(256) void vtrans_kernel(
    const unsigned short* __restrict__ v, unsigned short* __restrict__ vt)
{
    __shared__ __align__(16) unsigned short T[64][72];
    int bh = blockIdx.x, st = blockIdx.y;
    int t = threadIdx.x;
    int r = t >> 2, c = (t & 3) * 16;
    const unsigned short* src = v + ((size_t)bh * TLEN + st * 64) * DHH;
    short8 a0 = *(const short8*)(src + r * DHH + c);
    short8 a1 = *(const short8*)(src + r * DHH + c + 8);
    *(short8*)&T[r][c]     = a0;
    *(short8*)&T[r][c + 8] = a1;
    __syncthreads();
    int d = t >> 2;
    short8 o0, o1;
    #pragma unroll
    for (int j = 0; j < 8; j++) o0[j] = (short)T[c + j][d];
    #pragma unroll
    for (int j = 0; j < 8; j++) o1[j] = (short)T[c + 8 + j][d];
    unsigned short* dst = vt + ((size_t)bh * DHH + d) * TLEN + st * 64 + c;
    *(short8*)dst       = o0;
    *(short8*)(dst + 8) = o1;
}

// ---------------- fused LN (stats + apply in one pass) -----------------------
template<int F32IN>
__global__ __launch_bounds__(256) void ln_fused_kernel(
    const void* __restrict__ x, const float* __restrict__ g,
    const float* __restrict__ b, unsigned short* __restrict__ out)
{
    int row = blockIdx.x, tid = threadIdx.x;
    size_t off = (size_t)row * EDIM + tid * 4;
    float v0, v1, v2, v3;
    if (F32IN) {
        float4 a = *(const float4*)((const float*)x + off);
        v0 = a.x; v1 = a.y; v2 = a.z; v3 = a.w;
    } else {
        ushort4 raw = *(const ushort4*)((const unsigned short*)x + off);
        v0 = bf2f(raw.x); v1 = bf2f(raw.y); v2 = bf2f(raw.z); v3 = bf2f(raw.w);
    }
    float s  = v0 + v1 + v2 + v3;
    float ss = v0*v0 + v1*v1 + v2*v2 + v3*v3;
    #pragma unroll
    for (int o = 1; o < 64; o <<= 1) {
        s  += __shfl_xor(s,  o, 64);
        ss += __shfl_xor(ss, o, 64);
    }
    __shared__ float red[8];
    int wave = tid >> 6;
    if ((tid & 63) == 0) { red[wave*2] = s; red[wave*2+1] = ss; }
    __syncthreads();
    s  = red[0] + red[2] + red[4] + red[6];
    ss = red[1] + red[3] + red[5] + red[7];
    float m  = s * (1.0f / EDIM);
    float rs = rsqrtf(ss * (1.0f / EDIM) - m * m + 1e-5f);
    float4 gv = *(const float4*)(g + tid * 4);
    float4 bv = *(const float4*)(b + tid * 4);
    ushort4 o;
    o.x = f2bf((v0 - m) * rs * gv.x + bv.x);
    o.y = f2bf((v1 - m) * rs * gv.y + bv.y);
    o.z = f2bf((v2 - m) * rs * gv.z + bv.z);
    o.w = f2bf((v3 - m) * rs * gv.w + bv.w);
    *(ushort4*)(out + off) = o;
}

// ------------- gemm_bt64: BM=64, BN template (64/128), all variants ----------
// R10/R11: BM=64 -> more blocks/CU -> wave-level overlap of the barrier drain
// (m114 mechanism). m97 staging structure (global_load_lds, linear LDS).
// QKV reads 3 separate bias pointers directly (bias_fuse kernel removed).
#define V_QKV  0
#define V_WO   1
#define V_FF1  2
#define V_FF2A 3
#define V_FF2B 4

template<int VARIANT, int BN>
__global__ __launch_bounds__(256) void gemm_bt64_kernel(
    const unsigned short* A,        // bf16 [M][K]
    const unsigned short* Bt,       // bf16 [N][K]
    const float* bias,              // f32 (QKV: bq) (not read for FF2A)
    const float* bias2,             // QKV: bk ; else unused
    const float* bias3,             // QKV: bv ; else unused
    const void* resid,              // WO: f32 x ; FF2B: bf16 x1
    void* out,                      // QKV/FF1/WO: bf16 ; FF2A/B: f32 d_out
    int N, int K)
{
    constexpr int NJ = BN / 32;     // B frags per wave; also B gload issues
    __shared__ __align__(16) unsigned short As[64 * 64];
    __shared__ __align__(16) unsigned short Bs[BN * 64];
    int tid  = threadIdx.x;
    int lane = tid & 63, wave = tid >> 6;
    int quad = lane >> 4, l16 = lane & 15;
    int wr = wave >> 1, wc = wave & 1;        // 2x2 waves
    int m0 = blockIdx.y * 64, n0 = blockIdx.x * BN;

    f32x4 acc[2][NJ];
    #pragma unroll
    for (int i = 0; i < 2; i++)
        #pragma unroll
        for (int j = 0; j < NJ; j++) acc[i][j] = (f32x4){0.f, 0.f, 0.f, 0.f};

    int lr = lane >> 3;            // row within 8-row stripe
    int lc = (lane & 7) * 8;       // col elems (16B units)

    for (int k0 = 0; k0 < K; k0 += 64) {
        #pragma unroll
        for (int i = 0; i < 2; i++) {
            int blk = i * 4 + wave;            // 8 stripes cover 64 rows
            gload16(A + (size_t)(m0 + blk * 8 + lr) * K + k0 + lc, &As[blk * 512]);
        }
        #pragma unroll
        for (int i = 0; i < NJ; i++) {
            int blk = i * 4 + wave;            // BN/8 stripes cover BN rows
            gload16(Bt + (size_t)(n0 + blk * 8 + lr) * K + k0 + lc, &Bs[blk * 512]);
        }
        __syncthreads();           // vmcnt(0) drain: tile ready

        #pragma unroll
        for (int ks = 0; ks < 2; ks++) {
            short8 af[2], bf[NJ];
            #pragma unroll
            for (int i = 0; i < 2; i++)
                af[i] = *(const short8*)(&As[(wr * 32 + i * 16 + l16) * 64 + ks * 32 + quad * 8]);
            #pragma unroll
            for (int j = 0; j < NJ; j++)
                bf[j] = *(const short8*)(&Bs[(wc * (BN / 2) + j * 16 + l16) * 64 + ks * 32 + quad * 8]);
            #pragma unroll
            for (int i = 0; i < 2; i++)
                #pragma unroll
                for (int j = 0; j < NJ; j++)
                    acc[i][j] = __builtin_amdgcn_mfma_f32_16x16x32_bf16(af[i], bf[j], acc[i][j], 0, 0, 0);
        }

        __syncthreads();           // readers done before next stage overwrites
    }

    // epilogue: row = m0+wr*32+i*16+quad*4+r ; col = n0+wc*(BN/2)+j*16+l16
    #pragma unroll
    for (int j = 0; j < NJ; j++) {
        int c = n0 + wc * (BN / 2) + j * 16 + l16;
        float bi;
        if (VARIANT == V_QKV) {
            int mat = c >> 10, cc = c & 1023;
            bi = (mat == 0 ? bias : mat == 1 ? bias2 : bias3)[cc];
        } else {
            bi = (VARIANT == V_FF2A) ? 0.0f : bias[c];
        }
        #pragma unroll
        for (int i = 0; i < 2; i++) {
            #pragma unroll
            for (int r = 0; r < 4; r++) {
                int m = m0 + wr * 32 + i * 16 + quad * 4 + r;
                float val = acc[i][j][r] + bi;
                if (VARIANT == V_QKV) {
                    int b = m >> 11, t = m & 2047;
                    int mat = c >> 10, cc = c & 1023;
                    int h = cc >> 6, d = cc & 63;
                    if (mat == 0) val *= CS_SCALE;   // fold softmax scale into Q
                    ((unsigned short*)out)[(size_t)mat * 4194304 +
                        (((size_t)(b * NH + h)) * TLEN + t) * DHH + d] = f2bf(val);
                } else if (VARIANT == V_FF1) {
                    val = fmaxf(val, 0.0f);
                    ((unsigned short*)out)[(size_t)m * N + c] = f2bf(val);
                } else if (VARIANT == V_WO) {
                    val += ((const float*)resid)[(size_t)m * N + c];
                    ((unsigned short*)out)[(size_t)m * N + c] = f2bf(val);
                } else if (VARIANT == V_FF2A) {
                    ((float*)out)[(size_t)m * N + c] = val;
                } else {  // V_FF2B
                    val += bf2f(((const unsigned short*)resid)[(size_t)m * N + c])
                         + ((const float*)out)[(size_t)m * N + c];
                    ((float*)out)[(size_t)m * N + c] = val;
                }
            }
        }
    }
}

// ---------------- flash attention v8: swapped QK^T, in-lane P rows -----------
// v7.1 (62us): 6.1e6 bank-conflict cycles from 32 scalar u16 P-stores/chunk.
// v8: compute S' = mfma(K_frag, Q_frag) -> lane owns P[q=l16][s=n*16+quad*4+r]:
//  * adjacent s-pairs lane-local -> P packed to u32, 16 ds_write_b32 (half the
//    store instrs, fewer conflicts). P LDS layout + PV stage BIT-IDENTICAL to
//    the proven v7.1 ([q][s] row-major, stride 136).
//  * m,l are per-lane scalars (q=l16). Defer path: zero shuffles (__all over
//    lane-partial maxes == row-max check). Rescale: 2 shfl_xor for row max,
//    width-16 shfl to fetch alpha per o-row. Final 1/l via width-16 shfl.
//  * K/Q frag loads unchanged (same frags serve as A/B swapped; k-ranges align).
// Balanced tile pairing (R9) + pre-scaled Q (R10) retained.
__global__ __launch_bounds__(256) void attn_kernel(
    const unsigned short* __restrict__ q,
    const unsigned short* __restrict__ k,
    const unsigned short* __restrict__ vt,   // [bh][64 d][2048 s]
    unsigned short* __restrict__ att)
{
    __shared__ __align__(16) unsigned short Ks[128 * 72];     // 18.0 KB
    __shared__ __align__(16) unsigned short Vs[64 * 136];     // 17.0 KB
    __shared__ __align__(16) unsigned short Ps[4][16 * 136];  // 17.0 KB
    int tid  = threadIdx.x;
    int lane = tid & 63, wave = tid >> 6;
    int quad = lane >> 4, l16 = lane & 15;

    int flat = blockIdx.x;               // 0..511
    int xcd  = flat & 7, idx = flat >> 3;
    int bh   = xcd * 4 + (idx >> 4);     // 4 heads per XCD
    int pp   = idx & 15;                 // pair index: tiles pp and 31-pp

    const unsigned short* Kb = k  + (size_t)bh * TLEN * DHH;
    const unsigned short* Vb = vt + (size_t)bh * DHH * TLEN;
    unsigned short* Pw = Ps[wave];

    int rowK = tid >> 1, colK = (tid & 1) * 32;
    int rowV = tid >> 2, colV = (tid & 3) * 32;
    int bidx = bh >> 4, hh = bh & 15;

    for (int half = 0; half < 2; ++half) {
        int qt = half ? (31 - pp) : pp;
        int q0 = qt * 64;
        int qw = q0 + wave * 16;         // this wave's 16 q-rows
        int qme = qw + l16;              // this lane's q row (P ownership)

        const unsigned short* Qb = q + ((size_t)bh * TLEN + qw) * DHH;
        short8 aq0 = *(const short8*)(Qb + l16 * DHH + quad * 8);
        short8 aq1 = *(const short8*)(Qb + l16 * DHH + 32 + quad * 8);

        f32x4 o[4];
        #pragma unroll
        for (int n = 0; n < 4; n++) o[n] = (f32x4){0.f, 0.f, 0.f, 0.f};
        float mreg = -1e30f;             // running max for q=l16 (quad-synced)
        float lreg = 0.f;                // per-lane partial denominator

        int nch = (q0 >> 7) + 1;         // block-uniform (exact for all waves)

        // prefetch chunk 0 into registers
        short8 ka0, ka1, ka2, ka3, va0, va1, va2, va3;
        {
            const unsigned short* kp = Kb + (size_t)rowK * DHH + colK;
            ka0 = *(const short8*)kp;
            ka1 = *(const short8*)(kp + 8);
            ka2 = *(const short8*)(kp + 16);
            ka3 = *(const short8*)(kp + 24);
            const unsigned short* vp = Vb + (size_t)rowV * TLEN + colV;
            va0 = *(const short8*)vp;
            va1 = *(const short8*)(vp + 8);
            va2 = *(const short8*)(vp + 16);
            va3 = *(const short8*)(vp + 24);
        }

        for (int ch = 0; ch < nch; ch++) {
            int s0 = ch * 128;
            __syncthreads();             // all waves done reading prior chunk
            *(short8*)(&Ks[rowK * 72 + colK])       = ka0;
            *(short8*)(&Ks[rowK * 72 + colK + 8])   = ka1;
            *(short8*)(&Ks[rowK * 72 + colK + 16])  = ka2;
            *(short8*)(&Ks[rowK * 72 + colK + 24])  = ka3;
            *(short8*)(&Vs[rowV * 136 + colV])      = va0;
            *(short8*)(&Vs[rowV * 136 + colV + 8])  = va1;
            *(short8*)(&Vs[rowV * 136 + colV + 16]) = va2;
            *(short8*)(&Vs[rowV * 136 + colV + 24]) = va3;
            __syncthreads();             // staged

            if (ch + 1 < nch) {          // T14: next chunk's loads hide here
                int s1 = s0 + 128;
                const unsigned short* kp = Kb + (size_t)(s1 + rowK) * DHH + colK;
                ka0 = *(const short8*)kp;
                ka1 = *(const short8*)(kp + 8);
                ka2 = *(const short8*)(kp + 16);
                ka3 = *(const short8*)(kp + 24);
                const unsigned short* vp = Vb + (size_t)rowV * TLEN + s1 + colV;
                va0 = *(const short8*)vp;
                va1 = *(const short8*)(vp + 8);
                va2 = *(const short8*)(vp + 16);
                va3 = *(const short8*)(vp + 24);
            }

            // ---- QK^T swapped: S'[s=n*16+quad*4+r][q=l16] ----
            f32x4 S[8];
            #pragma unroll
            for (int n = 0; n < 8; n++) {
                short8 b0 = *(const short8*)(&Ks[(n * 16 + l16) * 72 + quad * 8]);
                short8 b1 = *(const short8*)(&Ks[(n * 16 + l16) * 72 + 32 + quad * 8]);
                f32x4 s = (f32x4){0.f, 0.f, 0.f, 0.f};
                s = __builtin_amdgcn_mfma_f32_16x16x32_bf16(b0, aq0, s, 0, 0, 0);
                s = __builtin_amdgcn_mfma_f32_16x16x32_bf16(b1, aq1, s, 0, 0, 0);
                S[n] = s;
            }
            bool needmask = (s0 + 127 > qw);  // wave-uniform; diag chunk(s)

            // ---- pass 1: mask + lane-local max over this lane's 32 s ----
            float mxl = -1e30f;
            #pragma unroll
            for (int n = 0; n < 8; n++) {
                #pragma unroll
                for (int r = 0; r < 4; r++) {
                    float xx = S[n][r];
                    if (needmask && (s0 + n * 16 + quad * 4 + r > qme)) xx = -1e30f;
                    S[n][r] = xx;
                    mxl = fmaxf(mxl, xx);
                }
            }
            // ---- defer-rescale (T13): zero shuffles on common path ----
            float used;
            if (__all(mxl <= mreg + 8.0f)) {
                used = mreg;
            } else {
                float mx = mxl;
                mx = fmaxf(mx, __shfl_xor(mx, 16, 64));
                mx = fmaxf(mx, __shfl_xor(mx, 32, 64));   // full row max (q=l16)
                float mnew  = fmaxf(mreg, mx);
                float alpha = fexp2(mreg - mnew);
                lreg *= alpha;
                #pragma unroll
                for (int r = 0; r < 4; r++) {
                    float ar = __shfl(alpha, quad * 4 + r, 16);  // alpha of o-row q
                    o[0][r] *= ar; o[1][r] *= ar;
                    o[2][r] *= ar; o[3][r] *= ar;
                }
                mreg = mnew;
                used = mnew;
            }
            // ---- pass 2: exp + packed u32 P-store + partial l ----
            #pragma unroll
            for (int n = 0; n < 8; n++) {
                float p0 = fexp2(S[n][0] - used);
                float p1 = fexp2(S[n][1] - used);
                float p2 = fexp2(S[n][2] - used);
                float p3 = fexp2(S[n][3] - used);
                lreg += (p0 + p1) + (p2 + p3);
                int sp = l16 * 136 + n * 16 + quad * 4;   // [q=l16][s base]
                *(unsigned int*)(Pw + sp)     = pack_bf2(p0, p1);
                *(unsigned int*)(Pw + sp + 2) = pack_bf2(p2, p3);
            }
            // ---- PV: O += P[16x128] * V[128x64] (unchanged, proven) ----
            short8 ap[4];
            #pragma unroll
            for (int ks = 0; ks < 4; ks++)
                ap[ks] = *(const short8*)(Pw + l16 * 136 + ks * 32 + quad * 8);
            #pragma unroll
            for (int n = 0; n < 4; n++) {
                #pragma unroll
                for (int ks = 0; ks < 4; ks++) {
                    short8 b = *(const short8*)(&Vs[(n * 16 + l16) * 136 + ks * 32 + quad * 8]);
                    o[n] = __builtin_amdgcn_mfma_f32_16x16x32_bf16(ap[ks], b, o[n], 0, 0, 0);
                }
            }
        }

        // ---- output this tile: full l = sum over quads; o-rows need q=quad*4+r
        float ls = lreg;
        ls += __shfl_xor(ls, 16, 64);
        ls += __shfl_xor(ls, 32, 64);
        float inv = 1.0f / ls;           // for q = l16
        #pragma unroll
        for (int r = 0; r < 4; r++) {
            float invr = __shfl(inv, quad * 4 + r, 16);
            int t = qw + quad * 4 + r;
            size_t rowoff = ((size_t)(bidx * TLEN + t)) * EDIM + hh * 64;
            #pragma unroll
            for (int n = 0; n < 4; n++)
                att[rowoff + n * 16 + l16] = f2bf(o[n][r] * invr);
        }
    }
}

// ---------------- launcher ----------------
extern "C" void kernel_launch(void* const* d_in, const int* in_sizes, int n_in,
                              void* d_out, int out_size, void* d_ws, size_t ws_size,
                              hipStream_t stream)
{
    (void)in_sizes; (void)n_in; (void)out_size; (void)ws_size;
    const float* x   = (const float*)d_in[0];
    const float* Wq  = (const float*)d_in[1];
    const float* bq  = (const float*)d_in[2];
    const float* Wk  = (const float*)d_in[3];
    const float* bk  = (const float*)d_in[4];
    const float* Wv  = (const float*)d_in[5];
    const float* bv  = (const float*)d_in[6];
    const float* Wo  = (const float*)d_in[7];
    const float* bo  = (const float*)d_in[8];
    const float* W1  = (const float*)d_in[9];
    const float* b1  = (const float*)d_in[10];
    const float* W2  = (const float*)d_in[11];
    const float* b2  = (const float*)d_in[12];
    const float* g1  = (const float*)d_in[13];
    const float* be1 = (const float*)d_in[14];
    const float* g2  = (const float*)d_in[15];
    const float* be2 = (const float*)d_in[16];

    // ws layout (ushort elems; total byte use < proven 42,008,640):
    //   xn/vtg/xn2 bytes 0..8M | q 8..16M (later x1) | k 16..24M (later WoT/W1T
    //   16..20M, W2T 20..24M) | v 24..32M | WqT/WkT/WvT 32..38M (contiguous
    //   [3072][1024] for fused QKV) then att 32..40M | h 24..40M (over v+att)
    unsigned short* ws  = (unsigned short*)d_ws;
    unsigned short* xn  = ws;                  // 4096x1024 bf16 (xn, vtg, xn2)
    unsigned short* vtg = ws;                  // V^T [32][64][2048] over xn
    unsigned short* qb  = ws + 4194304;        // q|k|v contiguous slots
    unsigned short* kb  = ws + 8388608;
    unsigned short* vb  = ws + 12582912;
    unsigned short* wqt = ws + 16777216;       // [3072][1024] fused Bt
    unsigned short* att = ws + 16777216;       // 4096x1024 bf16 (over WT, dead)
    unsigned short* x1  = ws + 4194304;        // over q (dead after attn)
    unsigned short* wot = ws + 8388608;        // over k (dead after attn)
    unsigned short* w1t = ws + 8388608;        // 2048x1024 bf16 (over WoT, dead)
    unsigned short* w2t = ws + 10485760;       // 1024x2048 bf16
    unsigned short* hb  = ws + 12582912;       // 4096x2048 bf16 (over v+att, dead)

    dim3 gT64(16, 16);                 // 1024x1024 transpose
    dim3 gE64(EDIM / 64, BT / 64);     // (16,64) = 1024 blocks, N=1024 gemms
    dim3 gQKV(3072 / 128, BT / 64);    // (24,64) = 1536 blocks, QKV BN=128
    dim3 gF(2048 / 128, BT / 64);      // (16,64) = 1024 blocks, FF1 BN=128

    // weight transposes for phase 1 (wqt/wkt/wvt contiguous), one launch
    transpose_qkv3_kernel<<<dim3(16, 16, 3), 256, 0, stream>>>(Wq, Wk, Wv, wqt);

    // LN1 -> xn (fused stats+apply)
    ln_fused_kernel<1><<<BT, 256, 0, stream>>>(x, g1, be1, xn);

    // fused QKV: one gemm, N=3072, BM=64/BN=128 (direct 3-pointer bias)
    gemm_bt64_kernel<V_QKV, 128><<<gQKV, 256, 0, stream>>>(xn, wqt, bq, bk, bv, nullptr, qb, 3072, EDIM);

    // V^T once per head (xn dead from here until LN2 rewrites it)
    vtrans_kernel<<<dim3(NH * 2, TLEN / 64), 256, 0, stream>>>(vb, vtg);

    attn_kernel<<<dim3(512), 256, 0, stream>>>(qb, kb, vtg, att);

    // WO (+resid x f32) -> x1 bf16  (BM=64: 1024 blocks, 4/CU)
    transpose_kernel<0><<<gT64, 256, 0, stream>>>(Wo, wot, EDIM, EDIM);
    gemm_bt64_kernel<V_WO, 64><<<gE64, 256, 0, stream>>>(att, wot, bo, nullptr, nullptr, x, x1, EDIM, EDIM);

    // LN2 -> xn2 (same slot as xn, fused stats+apply)
    ln_fused_kernel<0><<<BT, 256, 0, stream>>>(x1, g2, be2, xn);

    // FFN, split-K x2 to fit ws: h half = [4096][2048]
    // half A: W1[:, 0:2048], W2[0:2048, :]  (both transposes in one launch)
    transpose_ffn_kernel<<<dim3(32, 16, 2), 256, 0, stream>>>(W1, W2, w1t, w2t);
    gemm_bt64_kernel<V_FF1, 128><<<gF, 256, 0, stream>>>(xn, w1t, b1, nullptr, nullptr, nullptr, hb, 2048, EDIM);
    gemm_bt64_kernel<V_FF2A, 64><<<gE64, 256, 0, stream>>>(hb, w2t, nullptr, nullptr, nullptr, nullptr, d_out, EDIM, 2048);
    // half B: W1[:, 2048:4096], W2[2048:4096, :]
    transpose_ffn_kernel<<<dim3(32, 16, 2), 256, 0, stream>>>(W1 + 2048, W2 + (size_t)2048 * EDIM, w1t, w2t);
    gemm_bt64_kernel<V_FF1, 128><<<gF, 256, 0, stream>>>(xn, w1t, b1 + 2048, nullptr, nullptr, nullptr, hb, 2048, EDIM);
    gemm_bt64_kernel<V_FF2B, 64><<<gE64, 256, 0, stream>>>(hb, w2t, b2, nullptr, nullptr, x1, d_out, EDIM, 2048);
}